// Round 12
// baseline (642.215 us; speedup 1.0000x reference)
//
#include <hip/hip_runtime.h>
#include <hip/hip_bf16.h>
#include <hip/hip_cooperative_groups.h>

namespace cg = cooperative_groups;

#define B_  2
#define S_  2048
#define H_  1024
#define NH_ 16
#define HD_ 64
#define T_  (B_*S_)     // 4096 tokens
#define H3_ (3*H_)      // 3072

typedef float  floatx4 __attribute__((ext_vector_type(4)));
typedef __bf16 bf16x8  __attribute__((ext_vector_type(8)));

__device__ inline unsigned short f2bf_rn(float f) {
    union { float f; unsigned int u; } v; v.f = f;
    unsigned int u = v.u;
    u += 0x7fffu + ((u >> 16) & 1u);
    return (unsigned short)(u >> 16);
}
__device__ inline floatx4 fzero4() { floatx4 v; v[0]=0.f; v[1]=0.f; v[2]=0.f; v[3]=0.f; return v; }

__device__ inline float bf2f(unsigned short u) {
    union { unsigned int i; float f; } x; x.i = ((unsigned int)u) << 16; return x.f;
}

// pack two f32 -> one u32 of two bf16 (lo = src0), RNE; no builtin on gfx950 -> inline asm
__device__ inline unsigned int cvtpk_bf16(float lo, float hi) {
    unsigned int r;
    asm("v_cvt_pk_bf16_f32 %0, %1, %2" : "=v"(r) : "v"(lo), "v"(hi));
    return r;
}

// async global->LDS, 16B per lane; LDS dest = wave-uniform base + lane*16
__device__ inline void gload_lds16(const unsigned short* g, unsigned short* l) {
    __builtin_amdgcn_global_load_lds((const __attribute__((address_space(1))) unsigned int*)g,
                                     (__attribute__((address_space(3))) unsigned int*)l,
                                     16, 0, 0);
}

#define TLD 72
#define ALD 72
#define SCL2 0.1803368801f      /* 0.125 * log2(e) */
#define MNEG -14427.0f          /* -10000 * log2(e), causal fill */

__device__ unsigned int g_tk[3];   // dynamic-work tickets: [0]=qkv, [1]=attn, [2]=proj (reset each launch)

// ================================================================ fused cooperative kernel
// 4 phases separated by grid.sync(): pre (cvt+LN) -> qkv GEMM -> attention -> proj GEMM.
// r11 failed: 4 blocks/CU x 40960B = EXACTLY 160KiB -> cooperative occupancy rejected the launch
// (output stayed memset-zero). Fixes: (1) LDS arena 37120B (mask table bit-packed via __ballot:
// 256B instead of 4KB bf16) -> 148KB/CU with margin; (2) grid-size-agnostic phases: phase 1
// grid-strided, phases 2/3/4 consume device-global atomic tickets (heavy-first for attn -> no
// co-residency load imbalance); grid = min(1024, occupancy*256) chosen host-side; (3) host-side
// fallback to the proven r10 4-kernel path if the cooperative launch errors.
__global__ __launch_bounds__(256, 4) void fused_k(
        const float* __restrict__ qkvw, const float* __restrict__ ow,
        unsigned short* __restrict__ qkvwT, unsigned short* __restrict__ owT,
        const float* __restrict__ x, const float* __restrict__ nw, const float* __restrict__ nb,
        unsigned short* __restrict__ xn,
        const float* __restrict__ qkvb,
        unsigned short* __restrict__ Qg, unsigned short* __restrict__ Kgl, unsigned short* __restrict__ Vtg,
        const int* __restrict__ mask, unsigned short* __restrict__ ctxb,
        const float* __restrict__ ob, float* __restrict__ out)
{
    __shared__ __align__(16) char smem[37120];
    __shared__ unsigned int s_tk;
    const int bid = blockIdx.x;
    const int G   = gridDim.x;
    const int tid = threadIdx.x;
    const int lane = tid & 63;
    const int wave = tid >> 6;
    cg::grid_group grid = cg::this_grid();

    if (bid == 0 && tid < 3) g_tk[tid] = 0;

    // ================= phase 1a: weight cast+transpose (1024 units, grid-strided) =================
    {
        unsigned short* Ts = (unsigned short*)smem;    // 9216B
        for (int c = bid; c < 1024; c += G) {
            __syncthreads();                           // WAR on Ts across iterations
            int id = c;
            const float* W; unsigned short* Wt; int N, nbs, kb;
            if (id < 768) { W = qkvw; Wt = qkvwT; N = H3_; nbs = (id % 48) * 64; kb = (id / 48) * 64; }
            else { id -= 768; W = ow; Wt = owT; N = H_; nbs = (id % 16) * 64; kb = (id / 16) * 64; }
            const int K = H_;
            #pragma unroll
            for (int p = 0; p < 4; p++) {
                const int krow = kb + p * 16 + (tid >> 4);
                const int ncol = (tid & 15) * 4;
                const float4 w = *reinterpret_cast<const float4*>(&W[(size_t)krow * N + nbs + ncol]);
                Ts[(ncol + 0) * TLD + p * 16 + (tid >> 4)] = f2bf_rn(w.x);
                Ts[(ncol + 1) * TLD + p * 16 + (tid >> 4)] = f2bf_rn(w.y);
                Ts[(ncol + 2) * TLD + p * 16 + (tid >> 4)] = f2bf_rn(w.z);
                Ts[(ncol + 3) * TLD + p * 16 + (tid >> 4)] = f2bf_rn(w.w);
            }
            __syncthreads();
            #pragma unroll
            for (int p = 0; p < 2; p++) {
                const int n = (tid >> 3) + p * 32;
                const int k8 = (tid & 7) * 8;
                const uint4 v = *reinterpret_cast<const uint4*>(&Ts[n * TLD + k8]);
                *reinterpret_cast<uint4*>(&Wt[(size_t)(nbs + n) * K + kb + k8]) = v;
            }
        }
    }

    // ================= phase 1b: LayerNorm (4096 tokens, grid-strided) =================
    {
        float* red = (float*)smem;
        for (int t = bid; t < T_; t += G) {
            __syncthreads();                            // WAR on red / Ts
            const float4 v = reinterpret_cast<const float4*>(x + (size_t)t * H_)[tid];
            float s  = v.x + v.y + v.z + v.w;
            float s2 = v.x*v.x + v.y*v.y + v.z*v.z + v.w*v.w;
            for (int off = 32; off > 0; off >>= 1) {
                s  += __shfl_down(s,  off, 64);
                s2 += __shfl_down(s2, off, 64);
            }
            if (lane == 0) { red[wave] = s; red[4 + wave] = s2; }
            __syncthreads();
            if (tid == 0) {
                red[0] = red[0] + red[1] + red[2] + red[3];
                red[4] = red[4] + red[5] + red[6] + red[7];
            }
            __syncthreads();
            const float mean = red[0] * (1.f / H_);
            const float var  = red[4] * (1.f / H_) - mean * mean;
            const float rstd = rsqrtf(var + 1e-5f);
            const float4 wv = reinterpret_cast<const float4*>(nw)[tid];
            const float4 bv = reinterpret_cast<const float4*>(nb)[tid];
            ushort4 o = make_ushort4(f2bf_rn((v.x - mean) * rstd * wv.x + bv.x),
                                     f2bf_rn((v.y - mean) * rstd * wv.y + bv.y),
                                     f2bf_rn((v.z - mean) * rstd * wv.z + bv.z),
                                     f2bf_rn((v.w - mean) * rstd * wv.w + bv.w));
            reinterpret_cast<ushort4*>(xn + (size_t)t * H_)[tid] = o;
        }
    }

    __threadfence();
    grid.sync();
    __threadfence();

    // ================= phase 2: QKV GEMM (1536 128x64 tiles, ticket-dispatched) =================
    {
        unsigned short* As0 = (unsigned short*)(smem);           //  8192B
        unsigned short* As1 = (unsigned short*)(smem + 8192);    //  8192B
        unsigned short* Bs0 = (unsigned short*)(smem + 16384);   //  4096B
        unsigned short* Bs1 = (unsigned short*)(smem + 20480);   //  4096B
        const int K = H_;
        const int srow = lane >> 2;             // 0..15
        const int scol = (lane & 3) * 8;        // 0,8,16,24
        const int mrow = lane & 15;
        const int koff = (lane >> 4) * 8;
        const int col0 = lane & 15;
        const int r0   = (lane >> 4) * 4;

        for (;;) {
            if (tid == 0) s_tk = atomicAdd(&g_tk[0], 1u);
            __syncthreads();
            const unsigned int t = s_tk;
            if (t >= 1536u) break;
            const int mBase = ((int)t / 48) * 128;
            const int nBase = ((int)t % 48) * 64;    // x-major order (r7-measured locality)

            floatx4 acc[2][4];
            #pragma unroll
            for (int i = 0; i < 2; i++)
                #pragma unroll
                for (int j = 0; j < 4; j++) acc[i][j] = fzero4();

            for (int kb = 0; kb < K; kb += 64) {
                __syncthreads();
                #pragma unroll
                for (int p = 0; p < 2; p++) {
                    const int r = wave * 16 + p * 64;
                    const size_t ga = (size_t)(mBase + r + srow) * K + kb + scol;
                    gload_lds16(&xn[ga],      &As0[r * 32]);
                    gload_lds16(&xn[ga + 32], &As1[r * 32]);
                }
                {
                    const int r = wave * 16;
                    const size_t gb = (size_t)(nBase + r + srow) * K + kb + scol;
                    gload_lds16(&qkvwT[gb],      &Bs0[r * 32]);
                    gload_lds16(&qkvwT[gb + 32], &Bs1[r * 32]);
                }
                __syncthreads();

                #pragma unroll
                for (int half = 0; half < 2; half++) {
                    const unsigned short* As = half ? As1 : As0;
                    const unsigned short* Bs = half ? Bs1 : Bs0;
                    bf16x8 afrag[2], bfrag[4];
                    #pragma unroll
                    for (int mt = 0; mt < 2; mt++)
                        afrag[mt] = *reinterpret_cast<const bf16x8*>(&As[(wave * 32 + mt * 16 + mrow) * 32 + koff]);
                    #pragma unroll
                    for (int nt = 0; nt < 4; nt++)
                        bfrag[nt] = *reinterpret_cast<const bf16x8*>(&Bs[(nt * 16 + mrow) * 32 + koff]);
                    #pragma unroll
                    for (int mt = 0; mt < 2; mt++)
                        #pragma unroll
                        for (int nt = 0; nt < 4; nt++)
                            acc[mt][nt] = __builtin_amdgcn_mfma_f32_16x16x32_bf16(afrag[mt], bfrag[nt], acc[mt][nt], 0, 0, 0);
                }
            }

            const int hg  = nBase >> 6;               // block-uniform head index (0..47)
            const int sec = hg >> 4;                  // 0=q 1=k 2=v
            const int h   = hg & 15;

            float bs[4];
            #pragma unroll
            for (int nt = 0; nt < 4; nt++) bs[nt] = qkvb[nBase + nt * 16 + col0];

            if (sec < 2) {
                unsigned short* dst = (sec == 0) ? Qg : Kgl;
                const float if0 = __expf((float)col0        * (-0.2878231366f));   // j = col0
                const float if1 = __expf((float)(16 + col0) * (-0.2878231366f));   // j = 16+col0
                #pragma unroll
                for (int mt = 0; mt < 2; mt++) {
                    #pragma unroll
                    for (int reg = 0; reg < 4; reg++) {
                        const int tt = mBase + wave * 32 + mt * 16 + r0 + reg;
                        const int bb = tt >> 11;
                        const int s  = tt & (S_ - 1);
                        float sn0, cs0, sn1, cs1;
                        __sincosf((float)s * if0, &sn0, &cs0);
                        __sincosf((float)s * if1, &sn1, &cs1);
                        const float v0 = acc[mt][0][reg] + bs[0];   // d = col0
                        const float v1 = acc[mt][1][reg] + bs[1];   // d = 16+col0
                        const float v2 = acc[mt][2][reg] + bs[2];   // d = 32+col0
                        const float v3 = acc[mt][3][reg] + bs[3];   // d = 48+col0
                        const float o0 = v0 * cs0 - v2 * sn0;
                        const float o1 = v1 * cs1 - v3 * sn1;
                        const float o2 = v2 * cs0 + v0 * sn0;
                        const float o3 = v3 * cs1 + v1 * sn1;
                        const size_t rb = ((size_t)(bb * NH_ + h) * S_ + s) * HD_;
                        dst[rb +      col0] = f2bf_rn(o0);
                        dst[rb + 16 + col0] = f2bf_rn(o1);
                        dst[rb + 32 + col0] = f2bf_rn(o2);
                        dst[rb + 48 + col0] = f2bf_rn(o3);
                    }
                }
            } else {
                #pragma unroll
                for (int mt = 0; mt < 2; mt++) {
                    const int t0 = mBase + wave * 32 + mt * 16 + r0;   // 4 consecutive tokens
                    const int bb = t0 >> 11;
                    const int s0 = t0 & (S_ - 1);
                    #pragma unroll
                    for (int nt = 0; nt < 4; nt++) {
                        const int d = nt * 16 + col0;
                        ushort4 o;
                        o.x = f2bf_rn(acc[mt][nt][0] + bs[nt]);
                        o.y = f2bf_rn(acc[mt][nt][1] + bs[nt]);
                        o.z = f2bf_rn(acc[mt][nt][2] + bs[nt]);
                        o.w = f2bf_rn(acc[mt][nt][3] + bs[nt]);
                        *reinterpret_cast<ushort4*>(&Vtg[((size_t)(bb * NH_ + h) * HD_ + d) * S_ + s0]) = o;
                    }
                }
            }
        }
    }

    __threadfence();
    grid.sync();
    __threadfence();

    // ================= phase 3: attention (1024 units, ticket-dispatched heavy-first) =================
    {
        unsigned short* Ks0 = (unsigned short*)(smem);            // 9216B (key-permuted rows)
        unsigned short* Ks1 = (unsigned short*)(smem + 9216);     // 9216B
        unsigned short* Vt0 = (unsigned short*)(smem + 18432);    // 9216B (natural key order)
        unsigned short* Vt1 = (unsigned short*)(smem + 27648);    // 9216B
        unsigned long long* Mb64 = (unsigned long long*)(smem + 36864);  // 256B packed mask bits

        const int r16  = lane & 15;
        const int koff = (lane >> 4) * 8;
        const int g8   = (lane >> 4) * 8;
        const int srow = tid >> 3;          // 0..31
        const int scol = (tid & 7) * 8;
        const int pi = ((srow & 12) << 1) | (srow & 3) | (((srow >> 4) & 1) << 2);

        for (;;) {
            if (tid == 0) s_tk = atomicAdd(&g_tk[1], 1u);
            __syncthreads();
            const unsigned int u = s_tk;
            if (u >= 1024u) break;
            const int bh = (int)u & 31;
            const int v  = 31 - ((int)u >> 5);       // heavy-first ticket order
            const int b  = bh >> 4;
            const int h  = bh & 15;

            const size_t base = (size_t)bh * S_ * HD_;
            const int qbase = v * 64 + wave * 16;
            const int qcol = qbase + r16;

            // packed mask bits: one ballot word per 64 keys (bit set = masked out)
            #pragma unroll
            for (int j = 0; j < 8; j++) {
                const int widx = wave * 8 + j;
                const int mv = mask[b * S_ + widx * 64 + lane];
                const unsigned long long bal = __ballot(mv == 0);
                if (lane == 0) Mb64[widx] = bal;
            }

            const bf16x8 qf0 = *reinterpret_cast<const bf16x8*>(&Qg[base + (size_t)(qbase + r16) * HD_ + koff]);
            const bf16x8 qf1 = *reinterpret_cast<const bf16x8*>(&Qg[base + (size_t)(qbase + r16) * HD_ + 32 + koff]);

            bf16x8 onesA;
            #pragma unroll
            for (int q = 0; q < 8; q++) onesA[q] = (__bf16)1.f;

            floatx4 Ot[4];
            #pragma unroll
            for (int db = 0; db < 4; db++) Ot[db] = fzero4();
            floatx4 Lacc = fzero4();

            uint4 k00, k01, k10, k11, v00, v01, v10, v11;
#define PF_TILE(TT, KR0, KR1, VR0, VR1) do {                                                     \
        const int kb_ = (TT) * 64;                                                               \
        KR0 = *reinterpret_cast<const uint4*>(&Kgl[base + (size_t)(kb_ + pi)      * HD_ + scol]); \
        KR1 = *reinterpret_cast<const uint4*>(&Kgl[base + (size_t)(kb_ + 32 + pi) * HD_ + scol]); \
        VR0 = *reinterpret_cast<const uint4*>(&Vtg[base + (size_t)srow        * S_ + kb_ + scol]); \
        VR1 = *reinterpret_cast<const uint4*>(&Vtg[base + (size_t)(srow + 32) * S_ + kb_ + scol]); \
    } while (0)
#define PREFETCH_MACRO(MI) do {                                                                  \
        const int t0_ = min(2 * (MI), v);                                                        \
        const int t1_ = min(2 * (MI) + 1, v);                                                    \
        PF_TILE(t0_, k00, k01, v00, v01);                                                        \
        PF_TILE(t1_, k10, k11, v10, v11);                                                        \
    } while (0)

            const int nmac = (v + 2) >> 1;
            PREFETCH_MACRO(0);

            #pragma unroll 1
            for (int mi = 0; mi < nmac; mi++) {
                __syncthreads();                               // WAR: prior LDS reads done
                *reinterpret_cast<uint4*>(&Ks0[ srow       * ALD + scol]) = k00;
                *reinterpret_cast<uint4*>(&Ks0[(srow + 32) * ALD + scol]) = k01;
                *reinterpret_cast<uint4*>(&Ks1[ srow       * ALD + scol]) = k10;
                *reinterpret_cast<uint4*>(&Ks1[(srow + 32) * ALD + scol]) = k11;
                *reinterpret_cast<uint4*>(&Vt0[ srow       * ALD + scol]) = v00;
                *reinterpret_cast<uint4*>(&Vt0[(srow + 32) * ALD + scol]) = v01;
                *reinterpret_cast<uint4*>(&Vt1[ srow       * ALD + scol]) = v10;
                *reinterpret_cast<uint4*>(&Vt1[(srow + 32) * ALD + scol]) = v11;
                __syncthreads();                               // staged tiles + mask bits visible
                if (mi + 1 < nmac) PREFETCH_MACRO(mi + 1);

                #pragma unroll
                for (int half = 0; half < 2; half++) {
                    const int kt = 2 * mi + half;
                    if (half && kt > v) continue;              // wave-uniform skip
                    const int kb = kt * 64;
                    const unsigned short* ks = half ? Ks1 : Ks0;
                    const unsigned short* vs = half ? Vt1 : Vt0;
                    const unsigned long long mw = Mb64[kt];    // broadcast LDS read

                    #pragma unroll
                    for (int w = 0; w < 2; w++) {
                        float p[2][4];
                        #pragma unroll
                        for (int ab = 0; ab < 2; ab++) {
                            const int nt = w * 2 + ab;
                            const bf16x8 kf0 = *reinterpret_cast<const bf16x8*>(&ks[(nt * 16 + r16) * ALD + koff]);
                            const bf16x8 kf1 = *reinterpret_cast<const bf16x8*>(&ks[(nt * 16 + r16) * ALD + 32 + koff]);
                            floatx4 c = fzero4();
                            c = __builtin_amdgcn_mfma_f32_16x16x32_bf16(kf0, qf0, c, 0, 0, 0);
                            c = __builtin_amdgcn_mfma_f32_16x16x32_bf16(kf1, qf1, c, 0, 0, 0);
                            const int kbase = kb + w * 32 + ab * 4 + g8;
                            const unsigned int mq = (unsigned int)(mw >> (w * 32 + ab * 4 + g8)) & 0xFu;
                            float sc0 = c[0] * SCL2 + ((mq & 1u) ? MNEG : 0.f);
                            float sc1 = c[1] * SCL2 + ((mq & 2u) ? MNEG : 0.f);
                            float sc2 = c[2] * SCL2 + ((mq & 4u) ? MNEG : 0.f);
                            float sc3 = c[3] * SCL2 + ((mq & 8u) ? MNEG : 0.f);
                            if (kt == v) {                     // causal on diagonal tile only
                                if (kbase + 0 > qcol) sc0 = MNEG;
                                if (kbase + 1 > qcol) sc1 = MNEG;
                                if (kbase + 2 > qcol) sc2 = MNEG;
                                if (kbase + 3 > qcol) sc3 = MNEG;
                            }
                            p[ab][0] = exp2f(sc0);
                            p[ab][1] = exp2f(sc1);
                            p[ab][2] = exp2f(sc2);
                            p[ab][3] = exp2f(sc3);
                        }
                        union { uint4 u4; bf16x8 v8; } pf;
                        pf.u4.x = cvtpk_bf16(p[0][0], p[0][1]);
                        pf.u4.y = cvtpk_bf16(p[0][2], p[0][3]);
                        pf.u4.z = cvtpk_bf16(p[1][0], p[1][1]);
                        pf.u4.w = cvtpk_bf16(p[1][2], p[1][3]);
                        __builtin_amdgcn_s_setprio(1);
                        #pragma unroll
                        for (int db = 0; db < 4; db++) {
                            const bf16x8 vf = *reinterpret_cast<const bf16x8*>(&vs[(db * 16 + r16) * ALD + w * 32 + koff]);
                            Ot[db] = __builtin_amdgcn_mfma_f32_16x16x32_bf16(vf, pf.v8, Ot[db], 0, 0, 0);
                        }
                        Lacc = __builtin_amdgcn_mfma_f32_16x16x32_bf16(onesA, pf.v8, Lacc, 0, 0, 0);
                        __builtin_amdgcn_s_setprio(0);
                    }
                }
            }
#undef PREFETCH_MACRO
#undef PF_TILE

            const float rl = 1.f / Lacc[0];
            const int r4 = (lane >> 4) * 4;
            #pragma unroll
            for (int db = 0; db < 4; db++) {
                ushort4 o;
                o.x = f2bf_rn(Ot[db][0] * rl);
                o.y = f2bf_rn(Ot[db][1] * rl);
                o.z = f2bf_rn(Ot[db][2] * rl);
                o.w = f2bf_rn(Ot[db][3] * rl);
                *reinterpret_cast<ushort4*>(&ctxb[((size_t)b * S_ + qcol) * H_ + h * HD_ + db * 16 + r4]) = o;
            }
        }
    }

    __threadfence();
    grid.sync();
    __threadfence();

    // ================= phase 4: proj GEMM (512 units, ticket-dispatched) =================
    {
        unsigned short* As0 = (unsigned short*)(smem);
        unsigned short* As1 = (unsigned short*)(smem + 8192);
        unsigned short* Bs0 = (unsigned short*)(smem + 16384);
        unsigned short* Bs1 = (unsigned short*)(smem + 20480);
        const int K = H_, N = H_;
        const int srow = lane >> 2;
        const int scol = (lane & 3) * 8;
        const int mrow = lane & 15;
        const int koff = (lane >> 4) * 8;

        for (;;) {
            if (tid == 0) s_tk = atomicAdd(&g_tk[2], 1u);
            __syncthreads();
            const unsigned int t = s_tk;
            if (t >= 512u) break;
            const int nid = ((int)t & 7) * 64 + ((int)t >> 3);
            const int mBase = (nid >> 4) * 128;
            const int nBase = (nid & 15) * 64;

            floatx4 acc[2][4];
            #pragma unroll
            for (int i = 0; i < 2; i++)
                #pragma unroll
                for (int j = 0; j < 4; j++) acc[i][j] = fzero4();

            for (int kb = 0; kb < K; kb += 64) {
                __syncthreads();
                #pragma unroll
                for (int p = 0; p < 2; p++) {
                    const int r = wave * 16 + p * 64;
                    const size_t ga = (size_t)(mBase + r + srow) * K + kb + scol;
                    gload_lds16(&ctxb[ga],      &As0[r * 32]);
                    gload_lds16(&ctxb[ga + 32], &As1[r * 32]);
                }
                {
                    const int r = wave * 16;
                    const size_t gb = (size_t)(nBase + r + srow) * K + kb + scol;
                    gload_lds16(&owT[gb],      &Bs0[r * 32]);
                    gload_lds16(&owT[gb + 32], &Bs1[r * 32]);
                }
                __syncthreads();

                #pragma unroll
                for (int half = 0; half < 2; half++) {
                    const unsigned short* As = half ? As1 : As0;
                    const unsigned short* Bs = half ? Bs1 : Bs0;
                    bf16x8 afrag[2], bfrag[4];
                    #pragma unroll
                    for (int mt = 0; mt < 2; mt++)
                        afrag[mt] = *reinterpret_cast<const bf16x8*>(&As[(wave * 32 + mt * 16 + mrow) * 32 + koff]);
                    #pragma unroll
                    for (int nt = 0; nt < 4; nt++)
                        bfrag[nt] = *reinterpret_cast<const bf16x8*>(&Bs[(nt * 16 + mrow) * 32 + koff]);
                    #pragma unroll
                    for (int mt = 0; mt < 2; mt++)
                        #pragma unroll
                        for (int nt = 0; nt < 4; nt++)
                            acc[mt][nt] = __builtin_amdgcn_mfma_f32_16x16x32_bf16(afrag[mt], bfrag[nt], acc[mt][nt], 0, 0, 0);
                }
            }

            const int col0 = lane & 15;
            const int r0   = (lane >> 4) * 4;
            #pragma unroll
            for (int mt = 0; mt < 2; mt++) {
                #pragma unroll
                for (int nt = 0; nt < 4; nt++) {
                    const int gcol = nBase + nt * 16 + col0;
                    const float bsv = ob[gcol];
                    #pragma unroll
                    for (int reg = 0; reg < 4; reg++) {
                        const int grow = mBase + wave * 32 + mt * 16 + r0 + reg;
                        out[(size_t)grow * N + gcol] = acc[mt][nt][reg] + bsv;
                    }
                }
            }
        }
    }
}

// ================================================================ fallback path (r10, measured 185.7us)
__global__ __launch_bounds__(256) void pre_k(const float* __restrict__ qkvw,
                                             const float* __restrict__ ow,
                                             unsigned short* __restrict__ qkvwT,
                                             unsigned short* __restrict__ owT,
                                             const float* __restrict__ x,
                                             const float* __restrict__ nw,
                                             const float* __restrict__ nb,
                                             unsigned short* __restrict__ xn) {
    const int tid = threadIdx.x;
    if (blockIdx.x < 1024) {
        __shared__ unsigned short Ts[64 * TLD];
        int id = blockIdx.x;
        const float* W; unsigned short* Wt; int N, nbs, kb;
        if (id < 768) { W = qkvw; Wt = qkvwT; N = H3_; nbs = (id % 48) * 64; kb = (id / 48) * 64; }
        else { id -= 768; W = ow; Wt = owT; N = H_; nbs = (id % 16) * 64; kb = (id / 16) * 64; }
        const int K = H_;
        #pragma unroll
        for (int p = 0; p < 4; p++) {
            const int krow = kb + p * 16 + (tid >> 4);
            const int ncol = (tid & 15) * 4;
            const float4 w = *reinterpret_cast<const float4*>(&W[(size_t)krow * N + nbs + ncol]);
            Ts[(ncol + 0) * TLD + p * 16 + (tid >> 4)] = f2bf_rn(w.x);
            Ts[(ncol + 1) * TLD + p * 16 + (tid >> 4)] = f2bf_rn(w.y);
            Ts[(ncol + 2) * TLD + p * 16 + (tid >> 4)] = f2bf_rn(w.z);
            Ts[(ncol + 3) * TLD + p * 16 + (tid >> 4)] = f2bf_rn(w.w);
        }
        __syncthreads();
        #pragma unroll
        for (int p = 0; p < 2; p++) {
            const int n = (tid >> 3) + p * 32;
            const int k8 = (tid & 7) * 8;
            const uint4 v = *reinterpret_cast<const uint4*>(&Ts[n * TLD + k8]);
            *reinterpret_cast<uint4*>(&Wt[(size_t)(nbs + n) * K + kb + k8]) = v;
        }
    } else {
        const int t = blockIdx.x - 1024;
        const float4 v = reinterpret_cast<const float4*>(x + (size_t)t * H_)[tid];
        float s  = v.x + v.y + v.z + v.w;
        float s2 = v.x*v.x + v.y*v.y + v.z*v.z + v.w*v.w;
        for (int off = 32; off > 0; off >>= 1) {
            s  += __shfl_down(s,  off, 64);
            s2 += __shfl_down(s2, off, 64);
        }
        __shared__ float red[8];
        const int wave = tid >> 6, lane = tid & 63;
        if (lane == 0) { red[wave] = s; red[4 + wave] = s2; }
        __syncthreads();
        if (tid == 0) {
            red[0] = red[0] + red[1] + red[2] + red[3];
            red[4] = red[4] + red[5] + red[6] + red[7];
        }
        __syncthreads();
        const float mean = red[0] * (1.f / H_);
        const float var  = red[4] * (1.f / H_) - mean * mean;
        const float rstd = rsqrtf(var + 1e-5f);
        const float4 wv = reinterpret_cast<const float4*>(nw)[tid];
        const float4 bv = reinterpret_cast<const float4*>(nb)[tid];
        ushort4 o = make_ushort4(f2bf_rn((v.x - mean) * rstd * wv.x + bv.x),
                                 f2bf_rn((v.y - mean) * rstd * wv.y + bv.y),
                                 f2bf_rn((v.z - mean) * rstd * wv.z + bv.z),
                                 f2bf_rn((v.w - mean) * rstd * wv.w + bv.w));
        reinterpret_cast<ushort4*>(xn + (size_t)t * H_)[tid] = o;
    }
}

__global__ __launch_bounds__(256) void gemm_qkv_k(const unsigned short* __restrict__ A,
                                                  const unsigned short* __restrict__ Bt,
                                                  const float* __restrict__ bias,
                                                  unsigned short* __restrict__ Qo,
                                                  unsigned short* __restrict__ Ko,
                                                  unsigned short* __restrict__ Vto) {
    __shared__ unsigned short As0[128 * 32], As1[128 * 32];
    __shared__ unsigned short Bs0[ 64 * 32], Bs1[ 64 * 32];

    const int tid  = threadIdx.x;
    const int lane = tid & 63;
    const int wave = tid >> 6;
    const int mBase = blockIdx.y * 128;
    const int nBase = blockIdx.x * 64;
    const int K = H_;

    const int srow = lane >> 2;
    const int scol = (lane & 3) * 8;
    const int mrow = lane & 15;
    const int koff = (lane >> 4) * 8;

    floatx4 acc[2][4];
    #pragma unroll
    for (int i = 0; i < 2; i++)
        #pragma unroll
        for (int j = 0; j < 4; j++) acc[i][j] = fzero4();

    for (int kb = 0; kb < K; kb += 64) {
        __syncthreads();
        #pragma unroll
        for (int p = 0; p < 2; p++) {
            const int r = wave * 16 + p * 64;
            const size_t ga = (size_t)(mBase + r + srow) * K + kb + scol;
            gload_lds16(&A[ga],      &As0[r * 32]);
            gload_lds16(&A[ga + 32], &As1[r * 32]);
        }
        {
            const int r = wave * 16;
            const size_t gb = (size_t)(nBase + r + srow) * K + kb + scol;
            gload_lds16(&Bt[gb],      &Bs0[r * 32]);
            gload_lds16(&Bt[gb + 32], &Bs1[r * 32]);
        }
        __syncthreads();

        #pragma unroll
        for (int half = 0; half < 2; half++) {
            const unsigned short* As = half ? As1 : As0;
            const unsigned short* Bs = half ? Bs1 : Bs0;
            bf16x8 afrag[2], bfrag[4];
            #pragma unroll
            for (int mt = 0; mt < 2; mt++)
                afrag[mt] = *reinterpret_cast<const bf16x8*>(&As[(wave * 32 + mt * 16 + mrow) * 32 + koff]);
            #pragma unroll
            for (int nt = 0; nt < 4; nt++)
                bfrag[nt] = *reinterpret_cast<const bf16x8*>(&Bs[(nt * 16 + mrow) * 32 + koff]);
            #pragma unroll
            for (int mt = 0; mt < 2; mt++)
                #pragma unroll
                for (int nt = 0; nt < 4; nt++)
                    acc[mt][nt] = __builtin_amdgcn_mfma_f32_16x16x32_bf16(afrag[mt], bfrag[nt], acc[mt][nt], 0, 0, 0);
        }
    }

    const int col0 = lane & 15;
    const int r0   = (lane >> 4) * 4;
    const int hg   = nBase >> 6;
    const int sec  = hg >> 4;
    const int h    = hg & 15;

    float bs[4];
    #pragma unroll
    for (int nt = 0; nt < 4; nt++) bs[nt] = bias[nBase + nt * 16 + col0];

    if (sec < 2) {
        unsigned short* dst = (sec == 0) ? Qo : Ko;
        const float if0 = __expf((float)col0        * (-0.2878231366f));
        const float if1 = __expf((float)(16 + col0) * (-0.2878231366f));
        #pragma unroll
        for (int mt = 0; mt < 2; mt++) {
            #pragma unroll
            for (int reg = 0; reg < 4; reg++) {
                const int t  = mBase + wave * 32 + mt * 16 + r0 + reg;
                const int bb = t >> 11;
                const int s  = t & (S_ - 1);
                float sn0, cs0, sn1, cs1;
                __sincosf((float)s * if0, &sn0, &cs0);
                __sincosf((float)s * if1, &sn1, &cs1);
                const float v0 = acc[mt][0][reg] + bs[0];
                const float v1 = acc[mt][1][reg] + bs[1];
                const float v2 = acc[mt][2][reg] + bs[2];
                const float v3 = acc[mt][3][reg] + bs[3];
                const float o0 = v0 * cs0 - v2 * sn0;
                const float o1 = v1 * cs1 - v3 * sn1;
                const float o2 = v2 * cs0 + v0 * sn0;
                const float o3 = v3 * cs1 + v1 * sn1;
                const size_t rb = ((size_t)(bb * NH_ + h) * S_ + s) * HD_;
                dst[rb +      col0] = f2bf_rn(o0);
                dst[rb + 16 + col0] = f2bf_rn(o1);
                dst[rb + 32 + col0] = f2bf_rn(o2);
                dst[rb + 48 + col0] = f2bf_rn(o3);
            }
        }
    } else {
        #pragma unroll
        for (int mt = 0; mt < 2; mt++) {
            const int t0 = mBase + wave * 32 + mt * 16 + r0;
            const int bb = t0 >> 11;
            const int s0 = t0 & (S_ - 1);
            #pragma unroll
            for (int nt = 0; nt < 4; nt++) {
                const int d = nt * 16 + col0;
                ushort4 o;
                o.x = f2bf_rn(acc[mt][nt][0] + bs[nt]);
                o.y = f2bf_rn(acc[mt][nt][1] + bs[nt]);
                o.z = f2bf_rn(acc[mt][nt][2] + bs[nt]);
                o.w = f2bf_rn(acc[mt][nt][3] + bs[nt]);
                *reinterpret_cast<ushort4*>(&Vto[((size_t)(bb * NH_ + h) * HD_ + d) * S_ + s0]) = o;
            }
        }
    }
}

__global__ __launch_bounds__(256) void gemm_proj_k(const unsigned short* __restrict__ A,
                                                   const unsigned short* __restrict__ Bt,
                                                   const float* __restrict__ bias,
                                                   float* __restrict__ Cf,
                                                   int M, int N, int K) {
    __shared__ unsigned short As0[128 * 32], As1[128 * 32];
    __shared__ unsigned short Bs0[ 64 * 32], Bs1[ 64 * 32];

    const int tid  = threadIdx.x;
    const int lane = tid & 63;
    const int wave = tid >> 6;
    const int id  = blockIdx.x;
    const int nid = (id & 7) * 64 + (id >> 3);
    const int mBase = (nid >> 4) * 128;
    const int nBase = (nid & 15) * 64;

    const int srow = lane >> 2;
    const int scol = (lane & 3) * 8;
    const int mrow = lane & 15;
    const int koff = (lane >> 4) * 8;

    floatx4 acc[2][4];
    #pragma unroll
    for (int i = 0; i < 2; i++)
        #pragma unroll
        for (int j = 0; j < 4; j++) acc[i][j] = fzero4();

    for (int kb = 0; kb < K; kb += 64) {
        __syncthreads();
        #pragma unroll
        for (int p = 0; p < 2; p++) {
            const int r = wave * 16 + p * 64;
            const size_t ga = (size_t)(mBase + r + srow) * K + kb + scol;
            gload_lds16(&A[ga],      &As0[r * 32]);
            gload_lds16(&A[ga + 32], &As1[r * 32]);
        }
        {
            const int r = wave * 16;
            const size_t gb = (size_t)(nBase + r + srow) * K + kb + scol;
            gload_lds16(&Bt[gb],      &Bs0[r * 32]);
            gload_lds16(&Bt[gb + 32], &Bs1[r * 32]);
        }
        __syncthreads();

        #pragma unroll
        for (int half = 0; half < 2; half++) {
            const unsigned short* As = half ? As1 : As0;
            const unsigned short* Bs = half ? Bs1 : Bs0;
            bf16x8 afrag[2], bfrag[4];
            #pragma unroll
            for (int mt = 0; mt < 2; mt++)
                afrag[mt] = *reinterpret_cast<const bf16x8*>(&As[(wave * 32 + mt * 16 + mrow) * 32 + koff]);
            #pragma unroll
            for (int nt = 0; nt < 4; nt++)
                bfrag[nt] = *reinterpret_cast<const bf16x8*>(&Bs[(nt * 16 + mrow) * 32 + koff]);
            #pragma unroll
            for (int mt = 0; mt < 2; mt++)
                #pragma unroll
                for (int nt = 0; nt < 4; nt++)
                    acc[mt][nt] = __builtin_amdgcn_mfma_f32_16x16x32_bf16(afrag[mt], bfrag[nt], acc[mt][nt], 0, 0, 0);
        }
    }

    const int col0 = lane & 15;
    const int r0   = (lane >> 4) * 4;
    #pragma unroll
    for (int mt = 0; mt < 2; mt++) {
        #pragma unroll
        for (int nt = 0; nt < 4; nt++) {
            const int gcol = nBase + nt * 16 + col0;
            const float bsv = bias[gcol];
            #pragma unroll
            for (int reg = 0; reg < 4; reg++) {
                const int grow = mBase + wave * 32 + mt * 16 + r0 + reg;
                Cf[(size_t)grow * N + gcol] = acc[mt][nt][reg] + bsv;
            }
        }
    }
}

__global__ __launch_bounds__(256, 4) void attn_k(const unsigned short* __restrict__ Q,
                                                 const unsigned short* __restrict__ Kg,
                                                 const unsigned short* __restrict__ Vt,
                                                 const int* __restrict__ mask,
                                                 unsigned short* __restrict__ ctx) {
    const int id = blockIdx.x;
    const int bh = id & 31;
    const int v  = 31 - (id >> 5);
    const int b  = bh >> 4;
    const int h  = bh & 15;
    const int tid  = threadIdx.x;
    const int lane = tid & 63;
    const int wave = tid >> 6;

    __shared__ unsigned short Ks [2][64 * ALD];
    __shared__ unsigned short Vts[2][64 * ALD];
    __shared__ unsigned short Mb [S_];

    const size_t base = (size_t)bh * S_ * HD_;
    const int qbase = v * 64 + wave * 16;
    const int r16  = lane & 15;
    const int koff = (lane >> 4) * 8;
    const int g8   = (lane >> 4) * 8;
    const int qcol = qbase + r16;

    {
        const int k0 = tid * 8;
        const int4 ma = *reinterpret_cast<const int4*>(&mask[b * S_ + k0]);
        const int4 mc = *reinterpret_cast<const int4*>(&mask[b * S_ + k0 + 4]);
        union { unsigned short us[8]; uint4 q; } pk;
        pk.us[0] = f2bf_rn((1.f - (float)ma.x) * MNEG);
        pk.us[1] = f2bf_rn((1.f - (float)ma.y) * MNEG);
        pk.us[2] = f2bf_rn((1.f - (float)ma.z) * MNEG);
        pk.us[3] = f2bf_rn((1.f - (float)ma.w) * MNEG);
        pk.us[4] = f2bf_rn((1.f - (float)mc.x) * MNEG);
        pk.us[5] = f2bf_rn((1.f - (float)mc.y) * MNEG);
        pk.us[6] = f2bf_rn((1.f - (float)mc.z) * MNEG);
        pk.us[7] = f2bf_rn((1.f - (float)mc.w) * MNEG);
        *reinterpret_cast<uint4*>(&Mb[k0]) = pk.q;
    }

    const bf16x8 qf0 = *reinterpret_cast<const bf16x8*>(&Q[base + (size_t)(qbase + r16) * HD_ + koff]);
    const bf16x8 qf1 = *reinterpret_cast<const bf16x8*>(&Q[base + (size_t)(qbase + r16) * HD_ + 32 + koff]);

    bf16x8 onesA;
    #pragma unroll
    for (int q = 0; q < 8; q++) onesA[q] = (__bf16)1.f;

    floatx4 Ot[4];
    #pragma unroll
    for (int db = 0; db < 4; db++) Ot[db] = fzero4();
    floatx4 Lacc = fzero4();

    const int srow = tid >> 3;
    const int scol = (tid & 7) * 8;
    const int pi = ((srow & 12) << 1) | (srow & 3) | (((srow >> 4) & 1) << 2);

    uint4 k00, k01, k10, k11, v00, v01, v10, v11;
#define PF_TILE(TT, KR0, KR1, VR0, VR1) do {                                                   \
        const int kb_ = (TT) * 64;                                                             \
        KR0 = *reinterpret_cast<const uint4*>(&Kg[base + (size_t)(kb_ + pi)      * HD_ + scol]); \
        KR1 = *reinterpret_cast<const uint4*>(&Kg[base + (size_t)(kb_ + 32 + pi) * HD_ + scol]); \
        VR0 = *reinterpret_cast<const uint4*>(&Vt[base + (size_t)srow        * S_ + kb_ + scol]);  \
        VR1 = *reinterpret_cast<const uint4*>(&Vt[base + (size_t)(srow + 32) * S_ + kb_ + scol]);  \
    } while (0)
#define PREFETCH_MACRO(MI) do {                                                                \
        const int t0_ = min(2 * (MI), v);                                                      \
        const int t1_ = min(2 * (MI) + 1, v);                                                  \
        PF_TILE(t0_, k00, k01, v00, v01);                                                      \
        PF_TILE(t1_, k10, k11, v10, v11);                                                      \
    } while (0)

    const int nmac = (v + 2) >> 1;
    PREFETCH_MACRO(0);

    for (int mi = 0; mi < nmac; mi++) {
        if (mi) __syncthreads();
        *reinterpret_cast<uint4*>(&Ks [0][ srow       * ALD + scol]) = k00;
        *reinterpret_cast<uint4*>(&Ks [0][(srow + 32) * ALD + scol]) = k01;
        *reinterpret_cast<uint4*>(&Ks [1][ srow       * ALD + scol]) = k10;
        *reinterpret_cast<uint4*>(&Ks [1][(srow + 32) * ALD + scol]) = k11;
        *reinterpret_cast<uint4*>(&Vts[0][ srow       * ALD + scol]) = v00;
        *reinterpret_cast<uint4*>(&Vts[0][(srow + 32) * ALD + scol]) = v01;
        *reinterpret_cast<uint4*>(&Vts[1][ srow       * ALD + scol]) = v10;
        *reinterpret_cast<uint4*>(&Vts[1][(srow + 32) * ALD + scol]) = v11;
        __syncthreads();
        if (mi + 1 < nmac) PREFETCH_MACRO(mi + 1);

        #pragma unroll
        for (int half = 0; half < 2; half++) {
            const int kt = 2 * mi + half;
            if (half && kt > v) continue;
            const int kb = kt * 64;
            const unsigned short* ks = Ks [half];
            const unsigned short* vs = Vts[half];

            const unsigned short* mbp = &Mb[kb + g8];
            const ushort4 b00 = *reinterpret_cast<const ushort4*>(mbp);
            const ushort4 b01 = *reinterpret_cast<const ushort4*>(mbp + 4);
            const ushort4 b10 = *reinterpret_cast<const ushort4*>(mbp + 32);
            const ushort4 b11 = *reinterpret_cast<const ushort4*>(mbp + 36);

            #pragma unroll
            for (int w = 0; w < 2; w++) {
                float p[2][4];
                #pragma unroll
                for (int ab = 0; ab < 2; ab++) {
                    const int nt = w * 2 + ab;
                    const bf16x8 kf0 = *reinterpret_cast<const bf16x8*>(&ks[(nt * 16 + r16) * ALD + koff]);
                    const bf16x8 kf1 = *reinterpret_cast<const bf16x8*>(&ks[(nt * 16 + r16) * ALD + 32 + koff]);
                    floatx4 c = fzero4();
                    c = __builtin_amdgcn_mfma_f32_16x16x32_bf16(kf0, qf0, c, 0, 0, 0);
                    c = __builtin_amdgcn_mfma_f32_16x16x32_bf16(kf1, qf1, c, 0, 0, 0);
                    const ushort4 bb = w ? (ab ? b11 : b10) : (ab ? b01 : b00);
                    const int kbase = kb + w * 32 + ab * 4 + g8;
                    float sc0 = c[0] * SCL2 + bf2f(bb.x);
                    float sc1 = c[1] * SCL2 + bf2f(bb.y);
                    float sc2 = c[2] * SCL2 + bf2f(bb.z);
                    float sc3 = c[3] * SCL2 + bf2f(bb.w);
                    if (kt == v) {
                        if (kbase + 0 > qcol) sc0 = MNEG;
                        if (kbase + 1 > qcol) sc1 = MNEG;
                        if (kbase + 2 > qcol) sc2 = MNEG;
                        if (kbase + 3 > qcol) sc3 = MNEG;
                    }
                    p[ab][0] = exp2f(sc0);
                    p[ab][1] = exp2f(sc1);
                    p[ab][2] = exp2f(sc2);
                    p[ab][3] = exp2f(sc3);
                }
                union { uint4 u; bf16x8 v; } pf;
                pf.u.x = cvtpk_bf16(p[0][0], p[0][1]);
                pf.u.y = cvtpk_bf16(p[0][2], p[0][3]);
                pf.u.z = cvtpk_bf16(p[1][0], p[1][1]);
                pf.u.w = cvtpk_bf16(p[1][2], p[1][3]);
                __builtin_amdgcn_s_setprio(1);
                #pragma unroll
                for (int db = 0; db < 4; db++) {
                    const bf16x8 vf = *reinterpret_cast<const bf16x8*>(&vs[(db * 16 + r16) * ALD + w * 32 + koff]);
                    Ot[db] = __builtin_amdgcn_mfma_f32_16x16x32_bf16(vf, pf.v, Ot[db], 0, 0, 0);
                }
                Lacc = __builtin_amdgcn_mfma_f32_16x16x32_bf16(onesA, pf.v, Lacc, 0, 0, 0);
                __builtin_amdgcn_s_setprio(0);
            }
        }
    }
#undef PREFETCH_MACRO
#undef PF_TILE

    const float rl = 1.f / Lacc[0];
    const int r4 = (lane >> 4) * 4;
    #pragma unroll
    for (int db = 0; db < 4; db++) {
        ushort4 o;
        o.x = f2bf_rn(Ot[db][0] * rl);
        o.y = f2bf_rn(Ot[db][1] * rl);
        o.z = f2bf_rn(Ot[db][2] * rl);
        o.w = f2bf_rn(Ot[db][3] * rl);
        *reinterpret_cast<ushort4*>(&ctx[((size_t)b * S_ + qcol) * H_ + h * HD_ + db * 16 + r4]) = o;
    }
}

// ---------------------------------------------------------------- launch
extern "C" void kernel_launch(void* const* d_in, const int* in_sizes, int n_in,
                              void* d_out, int out_size, void* d_ws, size_t ws_size,
                              hipStream_t stream) {
    const float* x     = (const float*)d_in[0];
    const int*   mask  = (const int*)d_in[1];
    const float* normw = (const float*)d_in[2];
    const float* normb = (const float*)d_in[3];
    const float* qkvw  = (const float*)d_in[4];
    const float* qkvb  = (const float*)d_in[5];
    const float* ow    = (const float*)d_in[6];
    const float* ob    = (const float*)d_in[7];
    float* out = (float*)d_out;

    char* ws = (char*)d_ws;
    unsigned short* xn_bf   = (unsigned short*)(ws);                      //  8 MB
    unsigned short* qkvwT   = (unsigned short*)(ws + (8ull  << 20));      //  6 MB
    unsigned short* owT     = (unsigned short*)(ws + (14ull << 20));      //  2 MB
    unsigned short* Qb      = (unsigned short*)(ws + (16ull << 20));      //  8 MB [bh][s][d]
    unsigned short* Kb      = (unsigned short*)(ws + (24ull << 20));      //  8 MB [bh][s][d]
    unsigned short* Vtb     = (unsigned short*)(ws + (32ull << 20));      //  8 MB [bh][d][s]
    unsigned short* ctx_bf  = (unsigned short*)(ws + (40ull << 20));      //  8 MB

    static int coop_blocks = -1;
    if (coop_blocks < 0) {
        int nb = 0;
        hipError_t e = hipOccupancyMaxActiveBlocksPerMultiprocessor(&nb, fused_k, 256, 0);
        coop_blocks = (e == hipSuccess && nb >= 1) ? (nb > 4 ? 4 : nb) * 256 : 0;
        if (coop_blocks > 1024) coop_blocks = 1024;
    }
    if (coop_blocks > 0) {
        void* args[] = {
            (void*)&qkvw, (void*)&ow, (void*)&qkvwT, (void*)&owT,
            (void*)&x, (void*)&normw, (void*)&normb, (void*)&xn_bf,
            (void*)&qkvb,
            (void*)&Qb, (void*)&Kb, (void*)&Vtb,
            (void*)&mask, (void*)&ctx_bf,
            (void*)&ob, (void*)&out
        };
        if (hipLaunchCooperativeKernel((const void*)fused_k, dim3(coop_blocks), dim3(256),
                                       args, 0, stream) == hipSuccess)
            return;
        coop_blocks = 0;   // cooperative path unusable -> fall back permanently
    }

    // fallback: r10 four-kernel path (measured 185.7us)
    pre_k<<<1024 + T_, 256, 0, stream>>>(qkvw, ow, qkvwT, owT, x, normw, normb, xn_bf);
    gemm_qkv_k<<<dim3(H3_ / 64, T_ / 128), 256, 0, stream>>>(xn_bf, qkvwT, qkvb, Qb, Kb, Vtb);
    attn_k<<<1024, 256, 0, stream>>>(Qb, Kb, Vtb, mask, ctx_bf);
    gemm_proj_k<<<512, 256, 0, stream>>>(ctx_bf, owT, ob, out, T_, H_, H_);
}

// Round 13
// 184.630 us; speedup vs baseline: 3.4784x; 3.4784x over previous
//
#include <hip/hip_runtime.h>
#include <hip/hip_bf16.h>

#define B_  2
#define S_  2048
#define H_  1024
#define NH_ 16
#define HD_ 64
#define T_  (B_*S_)     // 4096 tokens
#define H3_ (3*H_)      // 3072

typedef float  floatx4 __attribute__((ext_vector_type(4)));
typedef __bf16 bf16x8  __attribute__((ext_vector_type(8)));

__device__ inline unsigned short f2bf_rn(float f) {
    union { float f; unsigned int u; } v; v.f = f;
    unsigned int u = v.u;
    u += 0x7fffu + ((u >> 16) & 1u);
    return (unsigned short)(u >> 16);
}
__device__ inline floatx4 fzero4() { floatx4 v; v[0]=0.f; v[1]=0.f; v[2]=0.f; v[3]=0.f; return v; }

__device__ inline float bf2f(unsigned short u) {
    union { unsigned int i; float f; } x; x.i = ((unsigned int)u) << 16; return x.f;
}

// pack two f32 -> one u32 of two bf16 (lo = src0), RNE; no builtin on gfx950 -> inline asm
__device__ inline unsigned int cvtpk_bf16(float lo, float hi) {
    unsigned int r;
    asm("v_cvt_pk_bf16_f32 %0, %1, %2" : "=v"(r) : "v"(lo), "v"(hi));
    return r;
}

// async global->LDS, 16B per lane; LDS dest = wave-uniform base + lane*16
__device__ inline void gload_lds16(const unsigned short* g, unsigned short* l) {
    __builtin_amdgcn_global_load_lds((const __attribute__((address_space(1))) unsigned int*)g,
                                     (__attribute__((address_space(3))) unsigned int*)l,
                                     16, 0, 0);
}

// ---------------------------------------------------------------- fused preprocessing: weight cast+transpose AND LayerNorm
// blocks 0..1023: cvt (768 qkvw tiles + 256 ow tiles); blocks 1024..5119: LN (one token each).
#define TLD 72
__global__ __launch_bounds__(256) void pre_k(const float* __restrict__ qkvw,
                                             const float* __restrict__ ow,
                                             unsigned short* __restrict__ qkvwT,
                                             unsigned short* __restrict__ owT,
                                             const float* __restrict__ x,
                                             const float* __restrict__ nw,
                                             const float* __restrict__ nb,
                                             unsigned short* __restrict__ xn) {
    const int tid = threadIdx.x;
    if (blockIdx.x < 1024) {
        __shared__ unsigned short Ts[64 * TLD];
        int id = blockIdx.x;
        const float* W; unsigned short* Wt; int N, nbs, kb;
        if (id < 768) { W = qkvw; Wt = qkvwT; N = H3_; nbs = (id % 48) * 64; kb = (id / 48) * 64; }
        else { id -= 768; W = ow; Wt = owT; N = H_; nbs = (id % 16) * 64; kb = (id / 16) * 64; }
        const int K = H_;
        #pragma unroll
        for (int p = 0; p < 4; p++) {
            const int krow = kb + p * 16 + (tid >> 4);
            const int ncol = (tid & 15) * 4;
            const float4 w = *reinterpret_cast<const float4*>(&W[(size_t)krow * N + nbs + ncol]);
            Ts[(ncol + 0) * TLD + p * 16 + (tid >> 4)] = f2bf_rn(w.x);
            Ts[(ncol + 1) * TLD + p * 16 + (tid >> 4)] = f2bf_rn(w.y);
            Ts[(ncol + 2) * TLD + p * 16 + (tid >> 4)] = f2bf_rn(w.z);
            Ts[(ncol + 3) * TLD + p * 16 + (tid >> 4)] = f2bf_rn(w.w);
        }
        __syncthreads();
        #pragma unroll
        for (int p = 0; p < 2; p++) {
            const int n = (tid >> 3) + p * 32;
            const int k8 = (tid & 7) * 8;
            const uint4 v = *reinterpret_cast<const uint4*>(&Ts[n * TLD + k8]);
            *reinterpret_cast<uint4*>(&Wt[(size_t)(nbs + n) * K + kb + k8]) = v;
        }
    } else {
        const int t = blockIdx.x - 1024;
        const float4 v = reinterpret_cast<const float4*>(x + (size_t)t * H_)[tid];
        float s  = v.x + v.y + v.z + v.w;
        float s2 = v.x*v.x + v.y*v.y + v.z*v.z + v.w*v.w;
        for (int off = 32; off > 0; off >>= 1) {
            s  += __shfl_down(s,  off, 64);
            s2 += __shfl_down(s2, off, 64);
        }
        __shared__ float red[8];
        const int wave = tid >> 6, lane = tid & 63;
        if (lane == 0) { red[wave] = s; red[4 + wave] = s2; }
        __syncthreads();
        if (tid == 0) {
            red[0] = red[0] + red[1] + red[2] + red[3];
            red[4] = red[4] + red[5] + red[6] + red[7];
        }
        __syncthreads();
        const float mean = red[0] * (1.f / H_);
        const float var  = red[4] * (1.f / H_) - mean * mean;
        const float rstd = rsqrtf(var + 1e-5f);
        const float4 wv = reinterpret_cast<const float4*>(nw)[tid];
        const float4 bv = reinterpret_cast<const float4*>(nb)[tid];
        ushort4 o = make_ushort4(f2bf_rn((v.x - mean) * rstd * wv.x + bv.x),
                                 f2bf_rn((v.y - mean) * rstd * wv.y + bv.y),
                                 f2bf_rn((v.z - mean) * rstd * wv.z + bv.z),
                                 f2bf_rn((v.w - mean) * rstd * wv.w + bv.w));
        reinterpret_cast<ushort4*>(xn + (size_t)t * H_)[tid] = o;
    }
}

// ---------------------------------------------------------------- QKV GEMM: 128x64 tiles, 2D x-major grid (r10: best measured)
__global__ __launch_bounds__(256) void gemm_qkv_k(const unsigned short* __restrict__ A,
                                                  const unsigned short* __restrict__ Bt,
                                                  const float* __restrict__ bias,
                                                  unsigned short* __restrict__ Qo,
                                                  unsigned short* __restrict__ Ko,
                                                  unsigned short* __restrict__ Vto) {
    __shared__ unsigned short As0[128 * 32], As1[128 * 32];
    __shared__ unsigned short Bs0[ 64 * 32], Bs1[ 64 * 32];

    const int tid  = threadIdx.x;
    const int lane = tid & 63;
    const int wave = tid >> 6;              // 0..3, owns rows wave*32..+31
    const int mBase = blockIdx.y * 128;
    const int nBase = blockIdx.x * 64;
    const int K = H_;

    const int srow = lane >> 2;             // 0..15
    const int scol = (lane & 3) * 8;        // 0,8,16,24
    const int mrow = lane & 15;
    const int koff = (lane >> 4) * 8;

    floatx4 acc[2][4];
    #pragma unroll
    for (int i = 0; i < 2; i++)
        #pragma unroll
        for (int j = 0; j < 4; j++) acc[i][j] = fzero4();

    for (int kb = 0; kb < K; kb += 64) {
        __syncthreads();
        #pragma unroll
        for (int p = 0; p < 2; p++) {
            const int r = wave * 16 + p * 64;
            const size_t ga = (size_t)(mBase + r + srow) * K + kb + scol;
            gload_lds16(&A[ga],      &As0[r * 32]);
            gload_lds16(&A[ga + 32], &As1[r * 32]);
        }
        {
            const int r = wave * 16;
            const size_t gb = (size_t)(nBase + r + srow) * K + kb + scol;
            gload_lds16(&Bt[gb],      &Bs0[r * 32]);
            gload_lds16(&Bt[gb + 32], &Bs1[r * 32]);
        }
        __syncthreads();

        #pragma unroll
        for (int half = 0; half < 2; half++) {
            const unsigned short* As = half ? As1 : As0;
            const unsigned short* Bs = half ? Bs1 : Bs0;
            bf16x8 afrag[2], bfrag[4];
            #pragma unroll
            for (int mt = 0; mt < 2; mt++)
                afrag[mt] = *reinterpret_cast<const bf16x8*>(&As[(wave * 32 + mt * 16 + mrow) * 32 + koff]);
            #pragma unroll
            for (int nt = 0; nt < 4; nt++)
                bfrag[nt] = *reinterpret_cast<const bf16x8*>(&Bs[(nt * 16 + mrow) * 32 + koff]);
            #pragma unroll
            for (int mt = 0; mt < 2; mt++)
                #pragma unroll
                for (int nt = 0; nt < 4; nt++)
                    acc[mt][nt] = __builtin_amdgcn_mfma_f32_16x16x32_bf16(afrag[mt], bfrag[nt], acc[mt][nt], 0, 0, 0);
        }
    }

    const int col0 = lane & 15;
    const int r0   = (lane >> 4) * 4;
    const int hg   = nBase >> 6;               // block-uniform head index (0..47)
    const int sec  = hg >> 4;                  // 0=q 1=k 2=v
    const int h    = hg & 15;

    float bs[4];
    #pragma unroll
    for (int nt = 0; nt < 4; nt++) bs[nt] = bias[nBase + nt * 16 + col0];

    if (sec < 2) {
        unsigned short* dst = (sec == 0) ? Qo : Ko;
        const float if0 = __expf((float)col0        * (-0.2878231366f));   // j = col0
        const float if1 = __expf((float)(16 + col0) * (-0.2878231366f));   // j = 16+col0
        #pragma unroll
        for (int mt = 0; mt < 2; mt++) {
            #pragma unroll
            for (int reg = 0; reg < 4; reg++) {
                const int t  = mBase + wave * 32 + mt * 16 + r0 + reg;
                const int bb = t >> 11;
                const int s  = t & (S_ - 1);
                float sn0, cs0, sn1, cs1;
                __sincosf((float)s * if0, &sn0, &cs0);
                __sincosf((float)s * if1, &sn1, &cs1);
                const float v0 = acc[mt][0][reg] + bs[0];   // d = col0
                const float v1 = acc[mt][1][reg] + bs[1];   // d = 16+col0
                const float v2 = acc[mt][2][reg] + bs[2];   // d = 32+col0
                const float v3 = acc[mt][3][reg] + bs[3];   // d = 48+col0
                const float o0 = v0 * cs0 - v2 * sn0;
                const float o1 = v1 * cs1 - v3 * sn1;
                const float o2 = v2 * cs0 + v0 * sn0;
                const float o3 = v3 * cs1 + v1 * sn1;
                const size_t rb = ((size_t)(bb * NH_ + h) * S_ + s) * HD_;
                dst[rb +      col0] = f2bf_rn(o0);
                dst[rb + 16 + col0] = f2bf_rn(o1);
                dst[rb + 32 + col0] = f2bf_rn(o2);
                dst[rb + 48 + col0] = f2bf_rn(o3);
            }
        }
    } else {
        #pragma unroll
        for (int mt = 0; mt < 2; mt++) {
            const int t0 = mBase + wave * 32 + mt * 16 + r0;   // 4 consecutive tokens, 4-aligned
            const int bb = t0 >> 11;
            const int s0 = t0 & (S_ - 1);
            #pragma unroll
            for (int nt = 0; nt < 4; nt++) {
                const int d = nt * 16 + col0;
                ushort4 o;
                o.x = f2bf_rn(acc[mt][nt][0] + bs[nt]);
                o.y = f2bf_rn(acc[mt][nt][1] + bs[nt]);
                o.z = f2bf_rn(acc[mt][nt][2] + bs[nt]);
                o.w = f2bf_rn(acc[mt][nt][3] + bs[nt]);
                *reinterpret_cast<ushort4*>(&Vto[((size_t)(bb * NH_ + h) * HD_ + d) * S_ + s0]) = o;
            }
        }
    }
}

// ---------------------------------------------------------------- proj GEMM: 128x64 tiles, 2D x-major grid
// (r8 lesson applied: the A-panel-per-XCD swizzle measured +13us/+14MB on qkv; proj now uses the
// same x-major 2D layout that measured best for qkv — 16 x-blocks -> 2 resident B-panels/XCD,
// lockstep A-walk with L3 dedup.)
__global__ __launch_bounds__(256) void gemm_proj_k(const unsigned short* __restrict__ A,
                                                   const unsigned short* __restrict__ Bt,
                                                   const float* __restrict__ bias,
                                                   float* __restrict__ Cf,
                                                   int M, int N, int K) {
    __shared__ unsigned short As0[128 * 32], As1[128 * 32];
    __shared__ unsigned short Bs0[ 64 * 32], Bs1[ 64 * 32];

    const int tid  = threadIdx.x;
    const int lane = tid & 63;
    const int wave = tid >> 6;              // 0..3, owns rows wave*32..+31
    const int mBase = blockIdx.y * 128;
    const int nBase = blockIdx.x * 64;

    const int srow = lane >> 2;             // 0..15
    const int scol = (lane & 3) * 8;        // 0,8,16,24
    const int mrow = lane & 15;
    const int koff = (lane >> 4) * 8;

    floatx4 acc[2][4];
    #pragma unroll
    for (int i = 0; i < 2; i++)
        #pragma unroll
        for (int j = 0; j < 4; j++) acc[i][j] = fzero4();

    for (int kb = 0; kb < K; kb += 64) {
        __syncthreads();
        #pragma unroll
        for (int p = 0; p < 2; p++) {
            const int r = wave * 16 + p * 64;
            const size_t ga = (size_t)(mBase + r + srow) * K + kb + scol;
            gload_lds16(&A[ga],      &As0[r * 32]);
            gload_lds16(&A[ga + 32], &As1[r * 32]);
        }
        {
            const int r = wave * 16;
            const size_t gb = (size_t)(nBase + r + srow) * K + kb + scol;
            gload_lds16(&Bt[gb],      &Bs0[r * 32]);
            gload_lds16(&Bt[gb + 32], &Bs1[r * 32]);
        }
        __syncthreads();

        #pragma unroll
        for (int half = 0; half < 2; half++) {
            const unsigned short* As = half ? As1 : As0;
            const unsigned short* Bs = half ? Bs1 : Bs0;
            bf16x8 afrag[2], bfrag[4];
            #pragma unroll
            for (int mt = 0; mt < 2; mt++)
                afrag[mt] = *reinterpret_cast<const bf16x8*>(&As[(wave * 32 + mt * 16 + mrow) * 32 + koff]);
            #pragma unroll
            for (int nt = 0; nt < 4; nt++)
                bfrag[nt] = *reinterpret_cast<const bf16x8*>(&Bs[(nt * 16 + mrow) * 32 + koff]);
            #pragma unroll
            for (int mt = 0; mt < 2; mt++)
                #pragma unroll
                for (int nt = 0; nt < 4; nt++)
                    acc[mt][nt] = __builtin_amdgcn_mfma_f32_16x16x32_bf16(afrag[mt], bfrag[nt], acc[mt][nt], 0, 0, 0);
        }
    }

    const int col0 = lane & 15;
    const int r0   = (lane >> 4) * 4;
    #pragma unroll
    for (int mt = 0; mt < 2; mt++) {
        #pragma unroll
        for (int nt = 0; nt < 4; nt++) {
            const int gcol = nBase + nt * 16 + col0;
            const float bsv = bias[gcol];
            #pragma unroll
            for (int reg = 0; reg < 4; reg++) {
                const int grow = mBase + wave * 32 + mt * 16 + r0 + reg;
                Cf[(size_t)grow * N + gcol] = acc[mt][nt][reg] + bsv;
            }
        }
    }
}

// ---------------------------------------------------------------- flash attention: in-register P + LDS mask-bias table
// (r10 structure, unchanged — swapped QK, key-permuted K staging, in-register P via cvt_pk,
// ones-A MFMA denominator, LDS bias table, setprio around PV cluster)
#define ALD 72
#define SCL2 0.1803368801f      /* 0.125 * log2(e) */
#define MNEG -14427.0f          /* -10000 * log2(e), causal fill */

__global__ __launch_bounds__(256, 4) void attn_k(const unsigned short* __restrict__ Q,
                                                 const unsigned short* __restrict__ Kg,
                                                 const unsigned short* __restrict__ Vt,
                                                 const int* __restrict__ mask,
                                                 unsigned short* __restrict__ ctx) {
    const int id = blockIdx.x;              // 0..1023
    const int bh = id & 31;                 // id%8 fixed per bh -> XCD locality
    const int v  = 31 - (id >> 5);          // q-tile index; most work first
    const int b  = bh >> 4;
    const int h  = bh & 15;
    const int tid  = threadIdx.x;
    const int lane = tid & 63;
    const int wave = tid >> 6;

    __shared__ unsigned short Ks [2][64 * ALD];   // 18.4 KB (key-permuted rows)
    __shared__ unsigned short Vts[2][64 * ALD];   // 18.4 KB (natural key order)
    __shared__ unsigned short Mb [S_];            //  4.0 KB bf16 mask-bias per key

    const size_t base = (size_t)bh * S_ * HD_;
    const int qbase = v * 64 + wave * 16;
    const int r16  = lane & 15;             // A-row / output-col lane index
    const int koff = (lane >> 4) * 8;       // d-offset in fragments / key-offset in PV reads
    const int g8   = (lane >> 4) * 8;       // key-group base for St quads
    const int qcol = qbase + r16;           // this lane's q row (output column)

    // ---- mask-bias table: 8 keys per thread, one b128 store; visible after first barrier
    {
        const int k0 = tid * 8;
        const int4 ma = *reinterpret_cast<const int4*>(&mask[b * S_ + k0]);
        const int4 mc = *reinterpret_cast<const int4*>(&mask[b * S_ + k0 + 4]);
        union { unsigned short us[8]; uint4 q; } pk;
        pk.us[0] = f2bf_rn((1.f - (float)ma.x) * MNEG);
        pk.us[1] = f2bf_rn((1.f - (float)ma.y) * MNEG);
        pk.us[2] = f2bf_rn((1.f - (float)ma.z) * MNEG);
        pk.us[3] = f2bf_rn((1.f - (float)ma.w) * MNEG);
        pk.us[4] = f2bf_rn((1.f - (float)mc.x) * MNEG);
        pk.us[5] = f2bf_rn((1.f - (float)mc.y) * MNEG);
        pk.us[6] = f2bf_rn((1.f - (float)mc.z) * MNEG);
        pk.us[7] = f2bf_rn((1.f - (float)mc.w) * MNEG);
        *reinterpret_cast<uint4*>(&Mb[k0]) = pk.q;
    }

    const bf16x8 qf0 = *reinterpret_cast<const bf16x8*>(&Q[base + (size_t)(qbase + r16) * HD_ + koff]);
    const bf16x8 qf1 = *reinterpret_cast<const bf16x8*>(&Q[base + (size_t)(qbase + r16) * HD_ + 32 + koff]);

    bf16x8 onesA;
    #pragma unroll
    for (int q = 0; q < 8; q++) onesA[q] = (__bf16)1.f;

    floatx4 Ot[4];                           // O^T: lane holds O^T[d=db*16+(lane>>4)*4+reg][q=qcol]
    #pragma unroll
    for (int db = 0; db < 4; db++) Ot[db] = fzero4();
    floatx4 Lacc = fzero4();                 // every row = column sum of P (ones-A MFMA)

    const int srow = tid >> 3;          // 0..31
    const int scol = (tid & 7) * 8;
    // key permutation within a 32-window: row r holds key pi(r)
    const int pi = ((srow & 12) << 1) | (srow & 3) | (((srow >> 4) & 1) << 2);

    // named prefetch registers for 2 tiles (no runtime-indexed arrays -> no scratch)
    uint4 k00, k01, k10, k11, v00, v01, v10, v11;
#define PF_TILE(TT, KR0, KR1, VR0, VR1) do {                                                   \
        const int kb_ = (TT) * 64;                                                             \
        KR0 = *reinterpret_cast<const uint4*>(&Kg[base + (size_t)(kb_ + pi)      * HD_ + scol]); \
        KR1 = *reinterpret_cast<const uint4*>(&Kg[base + (size_t)(kb_ + 32 + pi) * HD_ + scol]); \
        VR0 = *reinterpret_cast<const uint4*>(&Vt[base + (size_t)srow        * S_ + kb_ + scol]);  \
        VR1 = *reinterpret_cast<const uint4*>(&Vt[base + (size_t)(srow + 32) * S_ + kb_ + scol]);  \
    } while (0)
#define PREFETCH_MACRO(MI) do {                                                                \
        const int t0_ = min(2 * (MI), v);                                                      \
        const int t1_ = min(2 * (MI) + 1, v);                                                  \
        PF_TILE(t0_, k00, k01, v00, v01);                                                      \
        PF_TILE(t1_, k10, k11, v10, v11);                                                      \
    } while (0)

    const int nmac = (v + 2) >> 1;
    PREFETCH_MACRO(0);

    for (int mi = 0; mi < nmac; mi++) {
        if (mi) __syncthreads();                       // WAR: prior macro's LDS reads done
        *reinterpret_cast<uint4*>(&Ks [0][ srow       * ALD + scol]) = k00;
        *reinterpret_cast<uint4*>(&Ks [0][(srow + 32) * ALD + scol]) = k01;
        *reinterpret_cast<uint4*>(&Ks [1][ srow       * ALD + scol]) = k10;
        *reinterpret_cast<uint4*>(&Ks [1][(srow + 32) * ALD + scol]) = k11;
        *reinterpret_cast<uint4*>(&Vts[0][ srow       * ALD + scol]) = v00;
        *reinterpret_cast<uint4*>(&Vts[0][(srow + 32) * ALD + scol]) = v01;
        *reinterpret_cast<uint4*>(&Vts[1][ srow       * ALD + scol]) = v10;
        *reinterpret_cast<uint4*>(&Vts[1][(srow + 32) * ALD + scol]) = v11;
        __syncthreads();                               // staged tiles + (mi==0) Mb table visible
        if (mi + 1 < nmac) PREFETCH_MACRO(mi + 1);

        #pragma unroll
        for (int half = 0; half < 2; half++) {
            const int kt = 2 * mi + half;
            if (half && kt > v) continue;              // wave-uniform skip (odd tile count)
            const int kb = kt * 64;
            const unsigned short* ks = Ks [half];
            const unsigned short* vs = Vts[half];

            // ---- per-tile bias: four 8B broadcast LDS reads, latency hidden under QK
            const unsigned short* mbp = &Mb[kb + g8];
            const ushort4 b00 = *reinterpret_cast<const ushort4*>(mbp);        // w0 ab0
            const ushort4 b01 = *reinterpret_cast<const ushort4*>(mbp + 4);    // w0 ab1
            const ushort4 b10 = *reinterpret_cast<const ushort4*>(mbp + 32);   // w1 ab0
            const ushort4 b11 = *reinterpret_cast<const ushort4*>(mbp + 36);   // w1 ab1

            #pragma unroll
            for (int w = 0; w < 2; w++) {              // two 32-key windows
                float p[2][4];
                #pragma unroll
                for (int ab = 0; ab < 2; ab++) {
                    const int nt = w * 2 + ab;
                    // St = K·Q^T over permuted K rows; quad reg -> key kb + w*32 + ab*4 + 8g + reg
                    const bf16x8 kf0 = *reinterpret_cast<const bf16x8*>(&ks[(nt * 16 + r16) * ALD + koff]);
                    const bf16x8 kf1 = *reinterpret_cast<const bf16x8*>(&ks[(nt * 16 + r16) * ALD + 32 + koff]);
                    floatx4 c = fzero4();
                    c = __builtin_amdgcn_mfma_f32_16x16x32_bf16(kf0, qf0, c, 0, 0, 0);
                    c = __builtin_amdgcn_mfma_f32_16x16x32_bf16(kf1, qf1, c, 0, 0, 0);
                    const ushort4 bb = w ? (ab ? b11 : b10) : (ab ? b01 : b00);
                    const int kbase = kb + w * 32 + ab * 4 + g8;
                    float sc0 = c[0] * SCL2 + bf2f(bb.x);
                    float sc1 = c[1] * SCL2 + bf2f(bb.y);
                    float sc2 = c[2] * SCL2 + bf2f(bb.z);
                    float sc3 = c[3] * SCL2 + bf2f(bb.w);
                    if (kt == v) {                     // causal on diagonal tile only
                        if (kbase + 0 > qcol) sc0 = MNEG;
                        if (kbase + 1 > qcol) sc1 = MNEG;
                        if (kbase + 2 > qcol) sc2 = MNEG;
                        if (kbase + 3 > qcol) sc3 = MNEG;
                    }
                    p[ab][0] = exp2f(sc0);
                    p[ab][1] = exp2f(sc1);
                    p[ab][2] = exp2f(sc2);
                    p[ab][3] = exp2f(sc3);
                }
                // pack P fragment: keys w*32 + 8g + {0..7} in order
                union { uint4 u; bf16x8 v; } pf;
                pf.u.x = cvtpk_bf16(p[0][0], p[0][1]);
                pf.u.y = cvtpk_bf16(p[0][2], p[0][3]);
                pf.u.z = cvtpk_bf16(p[1][0], p[1][1]);
                pf.u.w = cvtpk_bf16(p[1][2], p[1][3]);
                // PV: O^T += V^T · P^T (V natural key order, contiguous reads); L via ones-A MFMA
                __builtin_amdgcn_s_setprio(1);
                #pragma unroll
                for (int db = 0; db < 4; db++) {
                    const bf16x8 vf = *reinterpret_cast<const bf16x8*>(&vs[(db * 16 + r16) * ALD + w * 32 + koff]);
                    Ot[db] = __builtin_amdgcn_mfma_f32_16x16x32_bf16(vf, pf.v, Ot[db], 0, 0, 0);
                }
                Lacc = __builtin_amdgcn_mfma_f32_16x16x32_bf16(onesA, pf.v, Lacc, 0, 0, 0);
                __builtin_amdgcn_s_setprio(0);
            }
        }
    }
#undef PREFETCH_MACRO
#undef PF_TILE

    // epilogue: Lacc rows all equal the full column sum — no cross-lane reduce needed
    const float rl = 1.f / Lacc[0];
    const int r4 = (lane >> 4) * 4;
    #pragma unroll
    for (int db = 0; db < 4; db++) {
        ushort4 o;
        o.x = f2bf_rn(Ot[db][0] * rl);
        o.y = f2bf_rn(Ot[db][1] * rl);
        o.z = f2bf_rn(Ot[db][2] * rl);
        o.w = f2bf_rn(Ot[db][3] * rl);
        *reinterpret_cast<ushort4*>(&ctx[((size_t)b * S_ + qcol) * H_ + h * HD_ + db * 16 + r4]) = o;
    }
}

// ---------------------------------------------------------------- launch
extern "C" void kernel_launch(void* const* d_in, const int* in_sizes, int n_in,
                              void* d_out, int out_size, void* d_ws, size_t ws_size,
                              hipStream_t stream) {
    const float* x     = (const float*)d_in[0];
    const int*   mask  = (const int*)d_in[1];
    const float* normw = (const float*)d_in[2];
    const float* normb = (const float*)d_in[3];
    const float* qkvw  = (const float*)d_in[4];
    const float* qkvb  = (const float*)d_in[5];
    const float* ow    = (const float*)d_in[6];
    const float* ob    = (const float*)d_in[7];
    float* out = (float*)d_out;

    char* ws = (char*)d_ws;
    unsigned short* xn_bf   = (unsigned short*)(ws);                      //  8 MB
    unsigned short* qkvwT   = (unsigned short*)(ws + (8ull  << 20));      //  6 MB
    unsigned short* owT     = (unsigned short*)(ws + (14ull << 20));      //  2 MB
    unsigned short* Qb      = (unsigned short*)(ws + (16ull << 20));      //  8 MB [bh][s][d]
    unsigned short* Kb      = (unsigned short*)(ws + (24ull << 20));      //  8 MB [bh][s][d]
    unsigned short* Vtb     = (unsigned short*)(ws + (32ull << 20));      //  8 MB [bh][d][s]
    unsigned short* ctx_bf  = (unsigned short*)(ws + (40ull << 20));      //  8 MB

    pre_k<<<1024 + T_, 256, 0, stream>>>(qkvw, ow, qkvwT, owT, x, normw, normb, xn_bf);
    gemm_qkv_k<<<dim3(H3_ / 64, T_ / 128), 256, 0, stream>>>(xn_bf, qkvwT, qkvb, Qb, Kb, Vtb);
    attn_k<<<1024, 256, 0, stream>>>(Qb, Kb, Vtb, mask, ctx_bf);
    gemm_proj_k<<<dim3(H_ / 64, T_ / 128), 256, 0, stream>>>(ctx_bf, owT, ob, out, T_, H_, H_);
}

// Round 14
// 180.984 us; speedup vs baseline: 3.5485x; 1.0201x over previous
//
#include <hip/hip_runtime.h>
#include <hip/hip_bf16.h>

#define B_  2
#define S_  2048
#define H_  1024
#define NH_ 16
#define HD_ 64
#define T_  (B_*S_)     // 4096 tokens
#define H3_ (3*H_)      // 3072

typedef float  floatx4 __attribute__((ext_vector_type(4)));
typedef __bf16 bf16x8  __attribute__((ext_vector_type(8)));

__device__ inline unsigned short f2bf_rn(float f) {
    union { float f; unsigned int u; } v; v.f = f;
    unsigned int u = v.u;
    u += 0x7fffu + ((u >> 16) & 1u);
    return (unsigned short)(u >> 16);
}
__device__ inline floatx4 fzero4() { floatx4 v; v[0]=0.f; v[1]=0.f; v[2]=0.f; v[3]=0.f; return v; }

__device__ inline float bf2f(unsigned short u) {
    union { unsigned int i; float f; } x; x.i = ((unsigned int)u) << 16; return x.f;
}

// pack two f32 -> one u32 of two bf16 (lo = src0), RNE; no builtin on gfx950 -> inline asm
__device__ inline unsigned int cvtpk_bf16(float lo, float hi) {
    unsigned int r;
    asm("v_cvt_pk_bf16_f32 %0, %1, %2" : "=v"(r) : "v"(lo), "v"(hi));
    return r;
}

// async global->LDS, 16B per lane; LDS dest = wave-uniform base + lane*16
__device__ inline void gload_lds16(const unsigned short* g, unsigned short* l) {
    __builtin_amdgcn_global_load_lds((const __attribute__((address_space(1))) unsigned int*)g,
                                     (__attribute__((address_space(3))) unsigned int*)l,
                                     16, 0, 0);
}

// ---------------------------------------------------------------- fused preprocessing: weight cast+transpose AND LayerNorm
// blocks 0..1023: cvt (768 qkvw tiles + 256 ow tiles); blocks 1024..5119: LN (one token each).
#define TLD 72
__global__ __launch_bounds__(256) void pre_k(const float* __restrict__ qkvw,
                                             const float* __restrict__ ow,
                                             unsigned short* __restrict__ qkvwT,
                                             unsigned short* __restrict__ owT,
                                             const float* __restrict__ x,
                                             const float* __restrict__ nw,
                                             const float* __restrict__ nb,
                                             unsigned short* __restrict__ xn) {
    const int tid = threadIdx.x;
    if (blockIdx.x < 1024) {
        __shared__ unsigned short Ts[64 * TLD];
        int id = blockIdx.x;
        const float* W; unsigned short* Wt; int N, nbs, kb;
        if (id < 768) { W = qkvw; Wt = qkvwT; N = H3_; nbs = (id % 48) * 64; kb = (id / 48) * 64; }
        else { id -= 768; W = ow; Wt = owT; N = H_; nbs = (id % 16) * 64; kb = (id / 16) * 64; }
        const int K = H_;
        #pragma unroll
        for (int p = 0; p < 4; p++) {
            const int krow = kb + p * 16 + (tid >> 4);
            const int ncol = (tid & 15) * 4;
            const float4 w = *reinterpret_cast<const float4*>(&W[(size_t)krow * N + nbs + ncol]);
            Ts[(ncol + 0) * TLD + p * 16 + (tid >> 4)] = f2bf_rn(w.x);
            Ts[(ncol + 1) * TLD + p * 16 + (tid >> 4)] = f2bf_rn(w.y);
            Ts[(ncol + 2) * TLD + p * 16 + (tid >> 4)] = f2bf_rn(w.z);
            Ts[(ncol + 3) * TLD + p * 16 + (tid >> 4)] = f2bf_rn(w.w);
        }
        __syncthreads();
        #pragma unroll
        for (int p = 0; p < 2; p++) {
            const int n = (tid >> 3) + p * 32;
            const int k8 = (tid & 7) * 8;
            const uint4 v = *reinterpret_cast<const uint4*>(&Ts[n * TLD + k8]);
            *reinterpret_cast<uint4*>(&Wt[(size_t)(nbs + n) * K + kb + k8]) = v;
        }
    } else {
        const int t = blockIdx.x - 1024;
        const float4 v = reinterpret_cast<const float4*>(x + (size_t)t * H_)[tid];
        float s  = v.x + v.y + v.z + v.w;
        float s2 = v.x*v.x + v.y*v.y + v.z*v.z + v.w*v.w;
        for (int off = 32; off > 0; off >>= 1) {
            s  += __shfl_down(s,  off, 64);
            s2 += __shfl_down(s2, off, 64);
        }
        __shared__ float red[8];
        const int wave = tid >> 6, lane = tid & 63;
        if (lane == 0) { red[wave] = s; red[4 + wave] = s2; }
        __syncthreads();
        if (tid == 0) {
            red[0] = red[0] + red[1] + red[2] + red[3];
            red[4] = red[4] + red[5] + red[6] + red[7];
        }
        __syncthreads();
        const float mean = red[0] * (1.f / H_);
        const float var  = red[4] * (1.f / H_) - mean * mean;
        const float rstd = rsqrtf(var + 1e-5f);
        const float4 wv = reinterpret_cast<const float4*>(nw)[tid];
        const float4 bv = reinterpret_cast<const float4*>(nb)[tid];
        ushort4 o = make_ushort4(f2bf_rn((v.x - mean) * rstd * wv.x + bv.x),
                                 f2bf_rn((v.y - mean) * rstd * wv.y + bv.y),
                                 f2bf_rn((v.z - mean) * rstd * wv.z + bv.z),
                                 f2bf_rn((v.w - mean) * rstd * wv.w + bv.w));
        reinterpret_cast<ushort4*>(xn + (size_t)t * H_)[tid] = o;
    }
}

// ---------------------------------------------------------------- QKV GEMM: 128x64 tiles, 2D x-major grid (r10: best measured)
__global__ __launch_bounds__(256) void gemm_qkv_k(const unsigned short* __restrict__ A,
                                                  const unsigned short* __restrict__ Bt,
                                                  const float* __restrict__ bias,
                                                  unsigned short* __restrict__ Qo,
                                                  unsigned short* __restrict__ Ko,
                                                  unsigned short* __restrict__ Vto) {
    __shared__ unsigned short As0[128 * 32], As1[128 * 32];
    __shared__ unsigned short Bs0[ 64 * 32], Bs1[ 64 * 32];

    const int tid  = threadIdx.x;
    const int lane = tid & 63;
    const int wave = tid >> 6;              // 0..3, owns rows wave*32..+31
    const int mBase = blockIdx.y * 128;
    const int nBase = blockIdx.x * 64;
    const int K = H_;

    const int srow = lane >> 2;             // 0..15
    const int scol = (lane & 3) * 8;        // 0,8,16,24
    const int mrow = lane & 15;
    const int koff = (lane >> 4) * 8;

    floatx4 acc[2][4];
    #pragma unroll
    for (int i = 0; i < 2; i++)
        #pragma unroll
        for (int j = 0; j < 4; j++) acc[i][j] = fzero4();

    for (int kb = 0; kb < K; kb += 64) {
        __syncthreads();
        #pragma unroll
        for (int p = 0; p < 2; p++) {
            const int r = wave * 16 + p * 64;
            const size_t ga = (size_t)(mBase + r + srow) * K + kb + scol;
            gload_lds16(&A[ga],      &As0[r * 32]);
            gload_lds16(&A[ga + 32], &As1[r * 32]);
        }
        {
            const int r = wave * 16;
            const size_t gb = (size_t)(nBase + r + srow) * K + kb + scol;
            gload_lds16(&Bt[gb],      &Bs0[r * 32]);
            gload_lds16(&Bt[gb + 32], &Bs1[r * 32]);
        }
        __syncthreads();

        #pragma unroll
        for (int half = 0; half < 2; half++) {
            const unsigned short* As = half ? As1 : As0;
            const unsigned short* Bs = half ? Bs1 : Bs0;
            bf16x8 afrag[2], bfrag[4];
            #pragma unroll
            for (int mt = 0; mt < 2; mt++)
                afrag[mt] = *reinterpret_cast<const bf16x8*>(&As[(wave * 32 + mt * 16 + mrow) * 32 + koff]);
            #pragma unroll
            for (int nt = 0; nt < 4; nt++)
                bfrag[nt] = *reinterpret_cast<const bf16x8*>(&Bs[(nt * 16 + mrow) * 32 + koff]);
            #pragma unroll
            for (int mt = 0; mt < 2; mt++)
                #pragma unroll
                for (int nt = 0; nt < 4; nt++)
                    acc[mt][nt] = __builtin_amdgcn_mfma_f32_16x16x32_bf16(afrag[mt], bfrag[nt], acc[mt][nt], 0, 0, 0);
        }
    }

    const int col0 = lane & 15;
    const int r0   = (lane >> 4) * 4;
    const int hg   = nBase >> 6;               // block-uniform head index (0..47)
    const int sec  = hg >> 4;                  // 0=q 1=k 2=v
    const int h    = hg & 15;

    float bs[4];
    #pragma unroll
    for (int nt = 0; nt < 4; nt++) bs[nt] = bias[nBase + nt * 16 + col0];

    if (sec < 2) {
        unsigned short* dst = (sec == 0) ? Qo : Ko;
        const float if0 = __expf((float)col0        * (-0.2878231366f));   // j = col0
        const float if1 = __expf((float)(16 + col0) * (-0.2878231366f));   // j = 16+col0
        #pragma unroll
        for (int mt = 0; mt < 2; mt++) {
            #pragma unroll
            for (int reg = 0; reg < 4; reg++) {
                const int t  = mBase + wave * 32 + mt * 16 + r0 + reg;
                const int bb = t >> 11;
                const int s  = t & (S_ - 1);
                float sn0, cs0, sn1, cs1;
                __sincosf((float)s * if0, &sn0, &cs0);
                __sincosf((float)s * if1, &sn1, &cs1);
                const float v0 = acc[mt][0][reg] + bs[0];   // d = col0
                const float v1 = acc[mt][1][reg] + bs[1];   // d = 16+col0
                const float v2 = acc[mt][2][reg] + bs[2];   // d = 32+col0
                const float v3 = acc[mt][3][reg] + bs[3];   // d = 48+col0
                const float o0 = v0 * cs0 - v2 * sn0;
                const float o1 = v1 * cs1 - v3 * sn1;
                const float o2 = v2 * cs0 + v0 * sn0;
                const float o3 = v3 * cs1 + v1 * sn1;
                const size_t rb = ((size_t)(bb * NH_ + h) * S_ + s) * HD_;
                dst[rb +      col0] = f2bf_rn(o0);
                dst[rb + 16 + col0] = f2bf_rn(o1);
                dst[rb + 32 + col0] = f2bf_rn(o2);
                dst[rb + 48 + col0] = f2bf_rn(o3);
            }
        }
    } else {
        #pragma unroll
        for (int mt = 0; mt < 2; mt++) {
            const int t0 = mBase + wave * 32 + mt * 16 + r0;   // 4 consecutive tokens, 4-aligned
            const int bb = t0 >> 11;
            const int s0 = t0 & (S_ - 1);
            #pragma unroll
            for (int nt = 0; nt < 4; nt++) {
                const int d = nt * 16 + col0;
                ushort4 o;
                o.x = f2bf_rn(acc[mt][nt][0] + bs[nt]);
                o.y = f2bf_rn(acc[mt][nt][1] + bs[nt]);
                o.z = f2bf_rn(acc[mt][nt][2] + bs[nt]);
                o.w = f2bf_rn(acc[mt][nt][3] + bs[nt]);
                *reinterpret_cast<ushort4*>(&Vto[((size_t)(bb * NH_ + h) * HD_ + d) * S_ + s0]) = o;
            }
        }
    }
}

// ---------------------------------------------------------------- proj GEMM: 128x64 tiles, 2D x-major grid (r13 config)
__global__ __launch_bounds__(256) void gemm_proj_k(const unsigned short* __restrict__ A,
                                                   const unsigned short* __restrict__ Bt,
                                                   const float* __restrict__ bias,
                                                   float* __restrict__ Cf,
                                                   int M, int N, int K) {
    __shared__ unsigned short As0[128 * 32], As1[128 * 32];
    __shared__ unsigned short Bs0[ 64 * 32], Bs1[ 64 * 32];

    const int tid  = threadIdx.x;
    const int lane = tid & 63;
    const int wave = tid >> 6;              // 0..3, owns rows wave*32..+31
    const int mBase = blockIdx.y * 128;
    const int nBase = blockIdx.x * 64;

    const int srow = lane >> 2;             // 0..15
    const int scol = (lane & 3) * 8;        // 0,8,16,24
    const int mrow = lane & 15;
    const int koff = (lane >> 4) * 8;

    floatx4 acc[2][4];
    #pragma unroll
    for (int i = 0; i < 2; i++)
        #pragma unroll
        for (int j = 0; j < 4; j++) acc[i][j] = fzero4();

    for (int kb = 0; kb < K; kb += 64) {
        __syncthreads();
        #pragma unroll
        for (int p = 0; p < 2; p++) {
            const int r = wave * 16 + p * 64;
            const size_t ga = (size_t)(mBase + r + srow) * K + kb + scol;
            gload_lds16(&A[ga],      &As0[r * 32]);
            gload_lds16(&A[ga + 32], &As1[r * 32]);
        }
        {
            const int r = wave * 16;
            const size_t gb = (size_t)(nBase + r + srow) * K + kb + scol;
            gload_lds16(&Bt[gb],      &Bs0[r * 32]);
            gload_lds16(&Bt[gb + 32], &Bs1[r * 32]);
        }
        __syncthreads();

        #pragma unroll
        for (int half = 0; half < 2; half++) {
            const unsigned short* As = half ? As1 : As0;
            const unsigned short* Bs = half ? Bs1 : Bs0;
            bf16x8 afrag[2], bfrag[4];
            #pragma unroll
            for (int mt = 0; mt < 2; mt++)
                afrag[mt] = *reinterpret_cast<const bf16x8*>(&As[(wave * 32 + mt * 16 + mrow) * 32 + koff]);
            #pragma unroll
            for (int nt = 0; nt < 4; nt++)
                bfrag[nt] = *reinterpret_cast<const bf16x8*>(&Bs[(nt * 16 + mrow) * 32 + koff]);
            #pragma unroll
            for (int mt = 0; mt < 2; mt++)
                #pragma unroll
                for (int nt = 0; nt < 4; nt++)
                    acc[mt][nt] = __builtin_amdgcn_mfma_f32_16x16x32_bf16(afrag[mt], bfrag[nt], acc[mt][nt], 0, 0, 0);
        }
    }

    const int col0 = lane & 15;
    const int r0   = (lane >> 4) * 4;
    #pragma unroll
    for (int mt = 0; mt < 2; mt++) {
        #pragma unroll
        for (int nt = 0; nt < 4; nt++) {
            const int gcol = nBase + nt * 16 + col0;
            const float bsv = bias[gcol];
            #pragma unroll
            for (int reg = 0; reg < 4; reg++) {
                const int grow = mBase + wave * 32 + mt * 16 + r0 + reg;
                Cf[(size_t)grow * N + gcol] = acc[mt][nt][reg] + bsv;
            }
        }
    }
}

// ---------------------------------------------------------------- flash attention: in-register P + LDS mask-bias table
// r13 structure + CU-balanced q-tile map: all 1024 blocks are co-resident (4/CU); CDNA dispatch puts
// blocks {c, c+256, c+512, c+768} on one CU. Old v=31-(id>>5) gave per-CU tile sums 84..52 (1.6x
// imbalance -> runtime = heaviest CU). Quarter map Q0:31-a Q1:16+a Q2:15-a Q3:a (a=(id&255)>>5)
// makes every CU quadruple sum to 66 tiles. Bijective over (bh,v); bh=id&31 XCD pinning unchanged.
#define ALD 72
#define SCL2 0.1803368801f      /* 0.125 * log2(e) */
#define MNEG -14427.0f          /* -10000 * log2(e), causal fill */

__global__ __launch_bounds__(256, 4) void attn_k(const unsigned short* __restrict__ Q,
                                                 const unsigned short* __restrict__ Kg,
                                                 const unsigned short* __restrict__ Vt,
                                                 const int* __restrict__ mask,
                                                 unsigned short* __restrict__ ctx) {
    const int id = blockIdx.x;              // 0..1023
    const int bh = id & 31;                 // id%8 fixed per bh -> XCD locality
    const int qa = (id & 255) >> 5;         // 0..7
    const int qq = id >> 8;                 // quarter 0..3
    const int v  = (qq == 0) ? (31 - qa) : (qq == 1) ? (16 + qa) : (qq == 2) ? (15 - qa) : qa;
    const int b  = bh >> 4;
    const int h  = bh & 15;
    const int tid  = threadIdx.x;
    const int lane = tid & 63;
    const int wave = tid >> 6;

    __shared__ unsigned short Ks [2][64 * ALD];   // 18.4 KB (key-permuted rows)
    __shared__ unsigned short Vts[2][64 * ALD];   // 18.4 KB (natural key order)
    __shared__ unsigned short Mb [S_];            //  4.0 KB bf16 mask-bias per key

    const size_t base = (size_t)bh * S_ * HD_;
    const int qbase = v * 64 + wave * 16;
    const int r16  = lane & 15;             // A-row / output-col lane index
    const int koff = (lane >> 4) * 8;       // d-offset in fragments / key-offset in PV reads
    const int g8   = (lane >> 4) * 8;       // key-group base for St quads
    const int qcol = qbase + r16;           // this lane's q row (output column)

    // ---- mask-bias table: 8 keys per thread, one b128 store; visible after first barrier
    {
        const int k0 = tid * 8;
        const int4 ma = *reinterpret_cast<const int4*>(&mask[b * S_ + k0]);
        const int4 mc = *reinterpret_cast<const int4*>(&mask[b * S_ + k0 + 4]);
        union { unsigned short us[8]; uint4 q; } pk;
        pk.us[0] = f2bf_rn((1.f - (float)ma.x) * MNEG);
        pk.us[1] = f2bf_rn((1.f - (float)ma.y) * MNEG);
        pk.us[2] = f2bf_rn((1.f - (float)ma.z) * MNEG);
        pk.us[3] = f2bf_rn((1.f - (float)ma.w) * MNEG);
        pk.us[4] = f2bf_rn((1.f - (float)mc.x) * MNEG);
        pk.us[5] = f2bf_rn((1.f - (float)mc.y) * MNEG);
        pk.us[6] = f2bf_rn((1.f - (float)mc.z) * MNEG);
        pk.us[7] = f2bf_rn((1.f - (float)mc.w) * MNEG);
        *reinterpret_cast<uint4*>(&Mb[k0]) = pk.q;
    }

    const bf16x8 qf0 = *reinterpret_cast<const bf16x8*>(&Q[base + (size_t)(qbase + r16) * HD_ + koff]);
    const bf16x8 qf1 = *reinterpret_cast<const bf16x8*>(&Q[base + (size_t)(qbase + r16) * HD_ + 32 + koff]);

    bf16x8 onesA;
    #pragma unroll
    for (int q = 0; q < 8; q++) onesA[q] = (__bf16)1.f;

    floatx4 Ot[4];                           // O^T: lane holds O^T[d=db*16+(lane>>4)*4+reg][q=qcol]
    #pragma unroll
    for (int db = 0; db < 4; db++) Ot[db] = fzero4();
    floatx4 Lacc = fzero4();                 // every row = column sum of P (ones-A MFMA)

    const int srow = tid >> 3;          // 0..31
    const int scol = (tid & 7) * 8;
    // key permutation within a 32-window: row r holds key pi(r)
    const int pi = ((srow & 12) << 1) | (srow & 3) | (((srow >> 4) & 1) << 2);

    // named prefetch registers for 2 tiles (no runtime-indexed arrays -> no scratch)
    uint4 k00, k01, k10, k11, v00, v01, v10, v11;
#define PF_TILE(TT, KR0, KR1, VR0, VR1) do {                                                   \
        const int kb_ = (TT) * 64;                                                             \
        KR0 = *reinterpret_cast<const uint4*>(&Kg[base + (size_t)(kb_ + pi)      * HD_ + scol]); \
        KR1 = *reinterpret_cast<const uint4*>(&Kg[base + (size_t)(kb_ + 32 + pi) * HD_ + scol]); \
        VR0 = *reinterpret_cast<const uint4*>(&Vt[base + (size_t)srow        * S_ + kb_ + scol]);  \
        VR1 = *reinterpret_cast<const uint4*>(&Vt[base + (size_t)(srow + 32) * S_ + kb_ + scol]);  \
    } while (0)
#define PREFETCH_MACRO(MI) do {                                                                \
        const int t0_ = min(2 * (MI), v);                                                      \
        const int t1_ = min(2 * (MI) + 1, v);                                                  \
        PF_TILE(t0_, k00, k01, v00, v01);                                                      \
        PF_TILE(t1_, k10, k11, v10, v11);                                                      \
    } while (0)

    const int nmac = (v + 2) >> 1;
    PREFETCH_MACRO(0);

    for (int mi = 0; mi < nmac; mi++) {
        if (mi) __syncthreads();                       // WAR: prior macro's LDS reads done
        *reinterpret_cast<uint4*>(&Ks [0][ srow       * ALD + scol]) = k00;
        *reinterpret_cast<uint4*>(&Ks [0][(srow + 32) * ALD + scol]) = k01;
        *reinterpret_cast<uint4*>(&Ks [1][ srow       * ALD + scol]) = k10;
        *reinterpret_cast<uint4*>(&Ks [1][(srow + 32) * ALD + scol]) = k11;
        *reinterpret_cast<uint4*>(&Vts[0][ srow       * ALD + scol]) = v00;
        *reinterpret_cast<uint4*>(&Vts[0][(srow + 32) * ALD + scol]) = v01;
        *reinterpret_cast<uint4*>(&Vts[1][ srow       * ALD + scol]) = v10;
        *reinterpret_cast<uint4*>(&Vts[1][(srow + 32) * ALD + scol]) = v11;
        __syncthreads();                               // staged tiles + (mi==0) Mb table visible
        if (mi + 1 < nmac) PREFETCH_MACRO(mi + 1);

        #pragma unroll
        for (int half = 0; half < 2; half++) {
            const int kt = 2 * mi + half;
            if (half && kt > v) continue;              // wave-uniform skip (odd tile count)
            const int kb = kt * 64;
            const unsigned short* ks = Ks [half];
            const unsigned short* vs = Vts[half];

            // ---- per-tile bias: four 8B broadcast LDS reads, latency hidden under QK
            const unsigned short* mbp = &Mb[kb + g8];
            const ushort4 b00 = *reinterpret_cast<const ushort4*>(mbp);        // w0 ab0
            const ushort4 b01 = *reinterpret_cast<const ushort4*>(mbp + 4);    // w0 ab1
            const ushort4 b10 = *reinterpret_cast<const ushort4*>(mbp + 32);   // w1 ab0
            const ushort4 b11 = *reinterpret_cast<const ushort4*>(mbp + 36);   // w1 ab1

            #pragma unroll
            for (int w = 0; w < 2; w++) {              // two 32-key windows
                float p[2][4];
                #pragma unroll
                for (int ab = 0; ab < 2; ab++) {
                    const int nt = w * 2 + ab;
                    // St = K·Q^T over permuted K rows; quad reg -> key kb + w*32 + ab*4 + 8g + reg
                    const bf16x8 kf0 = *reinterpret_cast<const bf16x8*>(&ks[(nt * 16 + r16) * ALD + koff]);
                    const bf16x8 kf1 = *reinterpret_cast<const bf16x8*>(&ks[(nt * 16 + r16) * ALD + 32 + koff]);
                    floatx4 c = fzero4();
                    c = __builtin_amdgcn_mfma_f32_16x16x32_bf16(kf0, qf0, c, 0, 0, 0);
                    c = __builtin_amdgcn_mfma_f32_16x16x32_bf16(kf1, qf1, c, 0, 0, 0);
                    const ushort4 bb = w ? (ab ? b11 : b10) : (ab ? b01 : b00);
                    const int kbase = kb + w * 32 + ab * 4 + g8;
                    float sc0 = c[0] * SCL2 + bf2f(bb.x);
                    float sc1 = c[1] * SCL2 + bf2f(bb.y);
                    float sc2 = c[2] * SCL2 + bf2f(bb.z);
                    float sc3 = c[3] * SCL2 + bf2f(bb.w);
                    if (kt == v) {                     // causal on diagonal tile only
                        if (kbase + 0 > qcol) sc0 = MNEG;
                        if (kbase + 1 > qcol) sc1 = MNEG;
                        if (kbase + 2 > qcol) sc2 = MNEG;
                        if (kbase + 3 > qcol) sc3 = MNEG;
                    }
                    p[ab][0] = exp2f(sc0);
                    p[ab][1] = exp2f(sc1);
                    p[ab][2] = exp2f(sc2);
                    p[ab][3] = exp2f(sc3);
                }
                // pack P fragment: keys w*32 + 8g + {0..7} in order
                union { uint4 u; bf16x8 v; } pf;
                pf.u.x = cvtpk_bf16(p[0][0], p[0][1]);
                pf.u.y = cvtpk_bf16(p[0][2], p[0][3]);
                pf.u.z = cvtpk_bf16(p[1][0], p[1][1]);
                pf.u.w = cvtpk_bf16(p[1][2], p[1][3]);
                // PV: O^T += V^T · P^T (V natural key order, contiguous reads); L via ones-A MFMA
                __builtin_amdgcn_s_setprio(1);
                #pragma unroll
                for (int db = 0; db < 4; db++) {
                    const bf16x8 vf = *reinterpret_cast<const bf16x8*>(&vs[(db * 16 + r16) * ALD + w * 32 + koff]);
                    Ot[db] = __builtin_amdgcn_mfma_f32_16x16x32_bf16(vf, pf.v, Ot[db], 0, 0, 0);
                }
                Lacc = __builtin_amdgcn_mfma_f32_16x16x32_bf16(onesA, pf.v, Lacc, 0, 0, 0);
                __builtin_amdgcn_s_setprio(0);
            }
        }
    }
#undef PREFETCH_MACRO
#undef PF_TILE

    // epilogue: Lacc rows all equal the full column sum — no cross-lane reduce needed
    const float rl = 1.f / Lacc[0];
    const int r4 = (lane >> 4) * 4;
    #pragma unroll
    for (int db = 0; db < 4; db++) {
        ushort4 o;
        o.x = f2bf_rn(Ot[db][0] * rl);
        o.y = f2bf_rn(Ot[db][1] * rl);
        o.z = f2bf_rn(Ot[db][2] * rl);
        o.w = f2bf_rn(Ot[db][3] * rl);
        *reinterpret_cast<ushort4*>(&ctx[((size_t)b * S_ + qcol) * H_ + h * HD_ + db * 16 + r4]) = o;
    }
}

// ---------------------------------------------------------------- launch
extern "C" void kernel_launch(void* const* d_in, const int* in_sizes, int n_in,
                              void* d_out, int out_size, void* d_ws, size_t ws_size,
                              hipStream_t stream) {
    const float* x     = (const float*)d_in[0];
    const int*   mask  = (const int*)d_in[1];
    const float* normw = (const float*)d_in[2];
    const float* normb = (const float*)d_in[3];
    const float* qkvw  = (const float*)d_in[4];
    const float* qkvb  = (const float*)d_in[5];
    const float* ow    = (const float*)d_in[6];
    const float* ob    = (const float*)d_in[7];
    float* out = (float*)d_out;

    char* ws = (char*)d_ws;
    unsigned short* xn_bf   = (unsigned short*)(ws);                      //  8 MB
    unsigned short* qkvwT   = (unsigned short*)(ws + (8ull  << 20));      //  6 MB
    unsigned short* owT     = (unsigned short*)(ws + (14ull << 20));      //  2 MB
    unsigned short* Qb      = (unsigned short*)(ws + (16ull << 20));      //  8 MB [bh][s][d]
    unsigned short* Kb      = (unsigned short*)(ws + (24ull << 20));      //  8 MB [bh][s][d]
    unsigned short* Vtb     = (unsigned short*)(ws + (32ull << 20));      //  8 MB [bh][d][s]
    unsigned short* ctx_bf  = (unsigned short*)(ws + (40ull << 20));      //  8 MB

    pre_k<<<1024 + T_, 256, 0, stream>>>(qkvw, ow, qkvwT, owT, x, normw, normb, xn_bf);
    gemm_qkv_k<<<dim3(H3_ / 64, T_ / 128), 256, 0, stream>>>(xn_bf, qkvwT, qkvb, Qb, Kb, Vtb);
    attn_k<<<1024, 256, 0, stream>>>(Qb, Kb, Vtb, mask, ctx_bf);
    gemm_proj_k<<<dim3(H_ / 64, T_ / 128), 256, 0, stream>>>(ctx_bf, owT, ob, out, T_, H_, H_);
}

// Round 15
// 174.627 us; speedup vs baseline: 3.6776x; 1.0364x over previous
//
#include <hip/hip_runtime.h>
#include <hip/hip_bf16.h>

#define B_  2
#define S_  2048
#define H_  1024
#define NH_ 16
#define HD_ 64
#define T_  (B_*S_)     // 4096 tokens
#define H3_ (3*H_)      // 3072

typedef float  floatx4 __attribute__((ext_vector_type(4)));
typedef __bf16 bf16x8  __attribute__((ext_vector_type(8)));

__device__ inline unsigned short f2bf_rn(float f) {
    union { float f; unsigned int u; } v; v.f = f;
    unsigned int u = v.u;
    u += 0x7fffu + ((u >> 16) & 1u);
    return (unsigned short)(u >> 16);
}
__device__ inline floatx4 fzero4() { floatx4 v; v[0]=0.f; v[1]=0.f; v[2]=0.f; v[3]=0.f; return v; }

__device__ inline float bf2f(unsigned short u) {
    union { unsigned int i; float f; } x; x.i = ((unsigned int)u) << 16; return x.f;
}

// pack two f32 -> one u32 of two bf16 (lo = src0), RNE; no builtin on gfx950 -> inline asm
__device__ inline unsigned int cvtpk_bf16(float lo, float hi) {
    unsigned int r;
    asm("v_cvt_pk_bf16_f32 %0, %1, %2" : "=v"(r) : "v"(lo), "v"(hi));
    return r;
}

// async global->LDS, 16B per lane; LDS dest = wave-uniform base + lane*16
__device__ inline void gload_lds16(const unsigned short* g, unsigned short* l) {
    __builtin_amdgcn_global_load_lds((const __attribute__((address_space(1))) unsigned int*)g,
                                     (__attribute__((address_space(3))) unsigned int*)l,
                                     16, 0, 0);
}

// ---------------------------------------------------------------- fused preprocessing: weight cast+transpose AND LayerNorm
// blocks 0..1023: cvt (768 qkvw tiles + 256 ow tiles); blocks 1024..5119: LN (one token each).
#define TLD 72
__global__ __launch_bounds__(256) void pre_k(const float* __restrict__ qkvw,
                                             const float* __restrict__ ow,
                                             unsigned short* __restrict__ qkvwT,
                                             unsigned short* __restrict__ owT,
                                             const float* __restrict__ x,
                                             const float* __restrict__ nw,
                                             const float* __restrict__ nb,
                                             unsigned short* __restrict__ xn) {
    const int tid = threadIdx.x;
    if (blockIdx.x < 1024) {
        __shared__ unsigned short Ts[64 * TLD];
        int id = blockIdx.x;
        const float* W; unsigned short* Wt; int N, nbs, kb;
        if (id < 768) { W = qkvw; Wt = qkvwT; N = H3_; nbs = (id % 48) * 64; kb = (id / 48) * 64; }
        else { id -= 768; W = ow; Wt = owT; N = H_; nbs = (id % 16) * 64; kb = (id / 16) * 64; }
        const int K = H_;
        #pragma unroll
        for (int p = 0; p < 4; p++) {
            const int krow = kb + p * 16 + (tid >> 4);
            const int ncol = (tid & 15) * 4;
            const float4 w = *reinterpret_cast<const float4*>(&W[(size_t)krow * N + nbs + ncol]);
            Ts[(ncol + 0) * TLD + p * 16 + (tid >> 4)] = f2bf_rn(w.x);
            Ts[(ncol + 1) * TLD + p * 16 + (tid >> 4)] = f2bf_rn(w.y);
            Ts[(ncol + 2) * TLD + p * 16 + (tid >> 4)] = f2bf_rn(w.z);
            Ts[(ncol + 3) * TLD + p * 16 + (tid >> 4)] = f2bf_rn(w.w);
        }
        __syncthreads();
        #pragma unroll
        for (int p = 0; p < 2; p++) {
            const int n = (tid >> 3) + p * 32;
            const int k8 = (tid & 7) * 8;
            const uint4 v = *reinterpret_cast<const uint4*>(&Ts[n * TLD + k8]);
            *reinterpret_cast<uint4*>(&Wt[(size_t)(nbs + n) * K + kb + k8]) = v;
        }
    } else {
        const int t = blockIdx.x - 1024;
        const float4 v = reinterpret_cast<const float4*>(x + (size_t)t * H_)[tid];
        float s  = v.x + v.y + v.z + v.w;
        float s2 = v.x*v.x + v.y*v.y + v.z*v.z + v.w*v.w;
        for (int off = 32; off > 0; off >>= 1) {
            s  += __shfl_down(s,  off, 64);
            s2 += __shfl_down(s2, off, 64);
        }
        __shared__ float red[8];
        const int wave = tid >> 6, lane = tid & 63;
        if (lane == 0) { red[wave] = s; red[4 + wave] = s2; }
        __syncthreads();
        if (tid == 0) {
            red[0] = red[0] + red[1] + red[2] + red[3];
            red[4] = red[4] + red[5] + red[6] + red[7];
        }
        __syncthreads();
        const float mean = red[0] * (1.f / H_);
        const float var  = red[4] * (1.f / H_) - mean * mean;
        const float rstd = rsqrtf(var + 1e-5f);
        const float4 wv = reinterpret_cast<const float4*>(nw)[tid];
        const float4 bv = reinterpret_cast<const float4*>(nb)[tid];
        ushort4 o = make_ushort4(f2bf_rn((v.x - mean) * rstd * wv.x + bv.x),
                                 f2bf_rn((v.y - mean) * rstd * wv.y + bv.y),
                                 f2bf_rn((v.z - mean) * rstd * wv.z + bv.z),
                                 f2bf_rn((v.w - mean) * rstd * wv.w + bv.w));
        reinterpret_cast<ushort4*>(xn + (size_t)t * H_)[tid] = o;
    }
}

// ---------------------------------------------------------------- QKV GEMM: 128x64 tiles, 2D x-major grid
// launch_bounds(256,5): cap VGPR at 102 (was 120 -> only 4 waves/SIMD; LDS 24.5KB allows 6 blocks/CU
// but VGPR capped residency at 4). 5 waves/SIMD = 20 waves/CU, +25% latency hiding; spill risk is
// confined to the rotary epilogue (off the hot loop).
__global__ __launch_bounds__(256, 5) void gemm_qkv_k(const unsigned short* __restrict__ A,
                                                     const unsigned short* __restrict__ Bt,
                                                     const float* __restrict__ bias,
                                                     unsigned short* __restrict__ Qo,
                                                     unsigned short* __restrict__ Ko,
                                                     unsigned short* __restrict__ Vto) {
    __shared__ unsigned short As0[128 * 32], As1[128 * 32];
    __shared__ unsigned short Bs0[ 64 * 32], Bs1[ 64 * 32];

    const int tid  = threadIdx.x;
    const int lane = tid & 63;
    const int wave = tid >> 6;              // 0..3, owns rows wave*32..+31
    const int mBase = blockIdx.y * 128;
    const int nBase = blockIdx.x * 64;
    const int K = H_;

    const int srow = lane >> 2;             // 0..15
    const int scol = (lane & 3) * 8;        // 0,8,16,24
    const int mrow = lane & 15;
    const int koff = (lane >> 4) * 8;

    floatx4 acc[2][4];
    #pragma unroll
    for (int i = 0; i < 2; i++)
        #pragma unroll
        for (int j = 0; j < 4; j++) acc[i][j] = fzero4();

    for (int kb = 0; kb < K; kb += 64) {
        __syncthreads();
        #pragma unroll
        for (int p = 0; p < 2; p++) {
            const int r = wave * 16 + p * 64;
            const size_t ga = (size_t)(mBase + r + srow) * K + kb + scol;
            gload_lds16(&A[ga],      &As0[r * 32]);
            gload_lds16(&A[ga + 32], &As1[r * 32]);
        }
        {
            const int r = wave * 16;
            const size_t gb = (size_t)(nBase + r + srow) * K + kb + scol;
            gload_lds16(&Bt[gb],      &Bs0[r * 32]);
            gload_lds16(&Bt[gb + 32], &Bs1[r * 32]);
        }
        __syncthreads();

        #pragma unroll
        for (int half = 0; half < 2; half++) {
            const unsigned short* As = half ? As1 : As0;
            const unsigned short* Bs = half ? Bs1 : Bs0;
            bf16x8 afrag[2], bfrag[4];
            #pragma unroll
            for (int mt = 0; mt < 2; mt++)
                afrag[mt] = *reinterpret_cast<const bf16x8*>(&As[(wave * 32 + mt * 16 + mrow) * 32 + koff]);
            #pragma unroll
            for (int nt = 0; nt < 4; nt++)
                bfrag[nt] = *reinterpret_cast<const bf16x8*>(&Bs[(nt * 16 + mrow) * 32 + koff]);
            #pragma unroll
            for (int mt = 0; mt < 2; mt++)
                #pragma unroll
                for (int nt = 0; nt < 4; nt++)
                    acc[mt][nt] = __builtin_amdgcn_mfma_f32_16x16x32_bf16(afrag[mt], bfrag[nt], acc[mt][nt], 0, 0, 0);
        }
    }

    const int col0 = lane & 15;
    const int r0   = (lane >> 4) * 4;
    const int hg   = nBase >> 6;               // block-uniform head index (0..47)
    const int sec  = hg >> 4;                  // 0=q 1=k 2=v
    const int h    = hg & 15;

    float bs[4];
    #pragma unroll
    for (int nt = 0; nt < 4; nt++) bs[nt] = bias[nBase + nt * 16 + col0];

    if (sec < 2) {
        unsigned short* dst = (sec == 0) ? Qo : Ko;
        const float if0 = __expf((float)col0        * (-0.2878231366f));   // j = col0
        const float if1 = __expf((float)(16 + col0) * (-0.2878231366f));   // j = 16+col0
        #pragma unroll
        for (int mt = 0; mt < 2; mt++) {
            #pragma unroll
            for (int reg = 0; reg < 4; reg++) {
                const int t  = mBase + wave * 32 + mt * 16 + r0 + reg;
                const int bb = t >> 11;
                const int s  = t & (S_ - 1);
                float sn0, cs0, sn1, cs1;
                __sincosf((float)s * if0, &sn0, &cs0);
                __sincosf((float)s * if1, &sn1, &cs1);
                const float v0 = acc[mt][0][reg] + bs[0];   // d = col0
                const float v1 = acc[mt][1][reg] + bs[1];   // d = 16+col0
                const float v2 = acc[mt][2][reg] + bs[2];   // d = 32+col0
                const float v3 = acc[mt][3][reg] + bs[3];   // d = 48+col0
                const float o0 = v0 * cs0 - v2 * sn0;
                const float o1 = v1 * cs1 - v3 * sn1;
                const float o2 = v2 * cs0 + v0 * sn0;
                const float o3 = v3 * cs1 + v1 * sn1;
                const size_t rb = ((size_t)(bb * NH_ + h) * S_ + s) * HD_;
                dst[rb +      col0] = f2bf_rn(o0);
                dst[rb + 16 + col0] = f2bf_rn(o1);
                dst[rb + 32 + col0] = f2bf_rn(o2);
                dst[rb + 48 + col0] = f2bf_rn(o3);
            }
        }
    } else {
        #pragma unroll
        for (int mt = 0; mt < 2; mt++) {
            const int t0 = mBase + wave * 32 + mt * 16 + r0;   // 4 consecutive tokens, 4-aligned
            const int bb = t0 >> 11;
            const int s0 = t0 & (S_ - 1);
            #pragma unroll
            for (int nt = 0; nt < 4; nt++) {
                const int d = nt * 16 + col0;
                ushort4 o;
                o.x = f2bf_rn(acc[mt][nt][0] + bs[nt]);
                o.y = f2bf_rn(acc[mt][nt][1] + bs[nt]);
                o.z = f2bf_rn(acc[mt][nt][2] + bs[nt]);
                o.w = f2bf_rn(acc[mt][nt][3] + bs[nt]);
                *reinterpret_cast<ushort4*>(&Vto[((size_t)(bb * NH_ + h) * HD_ + d) * S_ + s0]) = o;
            }
        }
    }
}

// ---------------------------------------------------------------- proj GEMM: 128x64 tiles, 2D x-major grid, waves/EU=5 cap
__global__ __launch_bounds__(256, 5) void gemm_proj_k(const unsigned short* __restrict__ A,
                                                      const unsigned short* __restrict__ Bt,
                                                      const float* __restrict__ bias,
                                                      float* __restrict__ Cf,
                                                      int M, int N, int K) {
    __shared__ unsigned short As0[128 * 32], As1[128 * 32];
    __shared__ unsigned short Bs0[ 64 * 32], Bs1[ 64 * 32];

    const int tid  = threadIdx.x;
    const int lane = tid & 63;
    const int wave = tid >> 6;              // 0..3, owns rows wave*32..+31
    const int mBase = blockIdx.y * 128;
    const int nBase = blockIdx.x * 64;

    const int srow = lane >> 2;             // 0..15
    const int scol = (lane & 3) * 8;        // 0,8,16,24
    const int mrow = lane & 15;
    const int koff = (lane >> 4) * 8;

    floatx4 acc[2][4];
    #pragma unroll
    for (int i = 0; i < 2; i++)
        #pragma unroll
        for (int j = 0; j < 4; j++) acc[i][j] = fzero4();

    for (int kb = 0; kb < K; kb += 64) {
        __syncthreads();
        #pragma unroll
        for (int p = 0; p < 2; p++) {
            const int r = wave * 16 + p * 64;
            const size_t ga = (size_t)(mBase + r + srow) * K + kb + scol;
            gload_lds16(&A[ga],      &As0[r * 32]);
            gload_lds16(&A[ga + 32], &As1[r * 32]);
        }
        {
            const int r = wave * 16;
            const size_t gb = (size_t)(nBase + r + srow) * K + kb + scol;
            gload_lds16(&Bt[gb],      &Bs0[r * 32]);
            gload_lds16(&Bt[gb + 32], &Bs1[r * 32]);
        }
        __syncthreads();

        #pragma unroll
        for (int half = 0; half < 2; half++) {
            const unsigned short* As = half ? As1 : As0;
            const unsigned short* Bs = half ? Bs1 : Bs0;
            bf16x8 afrag[2], bfrag[4];
            #pragma unroll
            for (int mt = 0; mt < 2; mt++)
                afrag[mt] = *reinterpret_cast<const bf16x8*>(&As[(wave * 32 + mt * 16 + mrow) * 32 + koff]);
            #pragma unroll
            for (int nt = 0; nt < 4; nt++)
                bfrag[nt] = *reinterpret_cast<const bf16x8*>(&Bs[(nt * 16 + mrow) * 32 + koff]);
            #pragma unroll
            for (int mt = 0; mt < 2; mt++)
                #pragma unroll
                for (int nt = 0; nt < 4; nt++)
                    acc[mt][nt] = __builtin_amdgcn_mfma_f32_16x16x32_bf16(afrag[mt], bfrag[nt], acc[mt][nt], 0, 0, 0);
        }
    }

    const int col0 = lane & 15;
    const int r0   = (lane >> 4) * 4;
    #pragma unroll
    for (int mt = 0; mt < 2; mt++) {
        #pragma unroll
        for (int nt = 0; nt < 4; nt++) {
            const int gcol = nBase + nt * 16 + col0;
            const float bsv = bias[gcol];
            #pragma unroll
            for (int reg = 0; reg < 4; reg++) {
                const int grow = mBase + wave * 32 + mt * 16 + r0 + reg;
                Cf[(size_t)grow * N + gcol] = acc[mt][nt][reg] + bsv;
            }
        }
    }
}

// ---------------------------------------------------------------- flash attention: in-register P + LDS mask-bias table
// (r14 structure, unchanged — swapped QK, key-permuted K staging, in-register P via cvt_pk,
// ones-A MFMA denominator, LDS bias table, setprio, CU-balanced q-tile map)
#define ALD 72
#define SCL2 0.1803368801f      /* 0.125 * log2(e) */
#define MNEG -14427.0f          /* -10000 * log2(e), causal fill */

__global__ __launch_bounds__(256, 4) void attn_k(const unsigned short* __restrict__ Q,
                                                 const unsigned short* __restrict__ Kg,
                                                 const unsigned short* __restrict__ Vt,
                                                 const int* __restrict__ mask,
                                                 unsigned short* __restrict__ ctx) {
    const int id = blockIdx.x;              // 0..1023
    const int bh = id & 31;                 // id%8 fixed per bh -> XCD locality
    const int qa = (id & 255) >> 5;         // 0..7
    const int qq = id >> 8;                 // quarter 0..3
    const int v  = (qq == 0) ? (31 - qa) : (qq == 1) ? (16 + qa) : (qq == 2) ? (15 - qa) : qa;
    const int b  = bh >> 4;
    const int h  = bh & 15;
    const int tid  = threadIdx.x;
    const int lane = tid & 63;
    const int wave = tid >> 6;

    __shared__ unsigned short Ks [2][64 * ALD];   // 18.4 KB (key-permuted rows)
    __shared__ unsigned short Vts[2][64 * ALD];   // 18.4 KB (natural key order)
    __shared__ unsigned short Mb [S_];            //  4.0 KB bf16 mask-bias per key

    const size_t base = (size_t)bh * S_ * HD_;
    const int qbase = v * 64 + wave * 16;
    const int r16  = lane & 15;             // A-row / output-col lane index
    const int koff = (lane >> 4) * 8;       // d-offset in fragments / key-offset in PV reads
    const int g8   = (lane >> 4) * 8;       // key-group base for St quads
    const int qcol = qbase + r16;           // this lane's q row (output column)

    // ---- mask-bias table: 8 keys per thread, one b128 store; visible after first barrier
    {
        const int k0 = tid * 8;
        const int4 ma = *reinterpret_cast<const int4*>(&mask[b * S_ + k0]);
        const int4 mc = *reinterpret_cast<const int4*>(&mask[b * S_ + k0 + 4]);
        union { unsigned short us[8]; uint4 q; } pk;
        pk.us[0] = f2bf_rn((1.f - (float)ma.x) * MNEG);
        pk.us[1] = f2bf_rn((1.f - (float)ma.y) * MNEG);
        pk.us[2] = f2bf_rn((1.f - (float)ma.z) * MNEG);
        pk.us[3] = f2bf_rn((1.f - (float)ma.w) * MNEG);
        pk.us[4] = f2bf_rn((1.f - (float)mc.x) * MNEG);
        pk.us[5] = f2bf_rn((1.f - (float)mc.y) * MNEG);
        pk.us[6] = f2bf_rn((1.f - (float)mc.z) * MNEG);
        pk.us[7] = f2bf_rn((1.f - (float)mc.w) * MNEG);
        *reinterpret_cast<uint4*>(&Mb[k0]) = pk.q;
    }

    const bf16x8 qf0 = *reinterpret_cast<const bf16x8*>(&Q[base + (size_t)(qbase + r16) * HD_ + koff]);
    const bf16x8 qf1 = *reinterpret_cast<const bf16x8*>(&Q[base + (size_t)(qbase + r16) * HD_ + 32 + koff]);

    bf16x8 onesA;
    #pragma unroll
    for (int q = 0; q < 8; q++) onesA[q] = (__bf16)1.f;

    floatx4 Ot[4];                           // O^T: lane holds O^T[d=db*16+(lane>>4)*4+reg][q=qcol]
    #pragma unroll
    for (int db = 0; db < 4; db++) Ot[db] = fzero4();
    floatx4 Lacc = fzero4();                 // every row = column sum of P (ones-A MFMA)

    const int srow = tid >> 3;          // 0..31
    const int scol = (tid & 7) * 8;
    // key permutation within a 32-window: row r holds key pi(r)
    const int pi = ((srow & 12) << 1) | (srow & 3) | (((srow >> 4) & 1) << 2);

    // named prefetch registers for 2 tiles (no runtime-indexed arrays -> no scratch)
    uint4 k00, k01, k10, k11, v00, v01, v10, v11;
#define PF_TILE(TT, KR0, KR1, VR0, VR1) do {                                                   \
        const int kb_ = (TT) * 64;                                                             \
        KR0 = *reinterpret_cast<const uint4*>(&Kg[base + (size_t)(kb_ + pi)      * HD_ + scol]); \
        KR1 = *reinterpret_cast<const uint4*>(&Kg[base + (size_t)(kb_ + 32 + pi) * HD_ + scol]); \
        VR0 = *reinterpret_cast<const uint4*>(&Vt[base + (size_t)srow        * S_ + kb_ + scol]);  \
        VR1 = *reinterpret_cast<const uint4*>(&Vt[base + (size_t)(srow + 32) * S_ + kb_ + scol]);  \
    } while (0)
#define PREFETCH_MACRO(MI) do {                                                                \
        const int t0_ = min(2 * (MI), v);                                                      \
        const int t1_ = min(2 * (MI) + 1, v);                                                  \
        PF_TILE(t0_, k00, k01, v00, v01);                                                      \
        PF_TILE(t1_, k10, k11, v10, v11);                                                      \
    } while (0)

    const int nmac = (v + 2) >> 1;
    PREFETCH_MACRO(0);

    for (int mi = 0; mi < nmac; mi++) {
        if (mi) __syncthreads();                       // WAR: prior macro's LDS reads done
        *reinterpret_cast<uint4*>(&Ks [0][ srow       * ALD + scol]) = k00;
        *reinterpret_cast<uint4*>(&Ks [0][(srow + 32) * ALD + scol]) = k01;
        *reinterpret_cast<uint4*>(&Ks [1][ srow       * ALD + scol]) = k10;
        *reinterpret_cast<uint4*>(&Ks [1][(srow + 32) * ALD + scol]) = k11;
        *reinterpret_cast<uint4*>(&Vts[0][ srow       * ALD + scol]) = v00;
        *reinterpret_cast<uint4*>(&Vts[0][(srow + 32) * ALD + scol]) = v01;
        *reinterpret_cast<uint4*>(&Vts[1][ srow       * ALD + scol]) = v10;
        *reinterpret_cast<uint4*>(&Vts[1][(srow + 32) * ALD + scol]) = v11;
        __syncthreads();                               // staged tiles + (mi==0) Mb table visible
        if (mi + 1 < nmac) PREFETCH_MACRO(mi + 1);

        #pragma unroll
        for (int half = 0; half < 2; half++) {
            const int kt = 2 * mi + half;
            if (half && kt > v) continue;              // wave-uniform skip (odd tile count)
            const int kb = kt * 64;
            const unsigned short* ks = Ks [half];
            const unsigned short* vs = Vts[half];

            // ---- per-tile bias: four 8B broadcast LDS reads, latency hidden under QK
            const unsigned short* mbp = &Mb[kb + g8];
            const ushort4 b00 = *reinterpret_cast<const ushort4*>(mbp);        // w0 ab0
            const ushort4 b01 = *reinterpret_cast<const ushort4*>(mbp + 4);    // w0 ab1
            const ushort4 b10 = *reinterpret_cast<const ushort4*>(mbp + 32);   // w1 ab0
            const ushort4 b11 = *reinterpret_cast<const ushort4*>(mbp + 36);   // w1 ab1

            #pragma unroll
            for (int w = 0; w < 2; w++) {              // two 32-key windows
                float p[2][4];
                #pragma unroll
                for (int ab = 0; ab < 2; ab++) {
                    const int nt = w * 2 + ab;
                    // St = K·Q^T over permuted K rows; quad reg -> key kb + w*32 + ab*4 + 8g + reg
                    const bf16x8 kf0 = *reinterpret_cast<const bf16x8*>(&ks[(nt * 16 + r16) * ALD + koff]);
                    const bf16x8 kf1 = *reinterpret_cast<const bf16x8*>(&ks[(nt * 16 + r16) * ALD + 32 + koff]);
                    floatx4 c = fzero4();
                    c = __builtin_amdgcn_mfma_f32_16x16x32_bf16(kf0, qf0, c, 0, 0, 0);
                    c = __builtin_amdgcn_mfma_f32_16x16x32_bf16(kf1, qf1, c, 0, 0, 0);
                    const ushort4 bb = w ? (ab ? b11 : b10) : (ab ? b01 : b00);
                    const int kbase = kb + w * 32 + ab * 4 + g8;
                    float sc0 = c[0] * SCL2 + bf2f(bb.x);
                    float sc1 = c[1] * SCL2 + bf2f(bb.y);
                    float sc2 = c[2] * SCL2 + bf2f(bb.z);
                    float sc3 = c[3] * SCL2 + bf2f(bb.w);
                    if (kt == v) {                     // causal on diagonal tile only
                        if (kbase + 0 > qcol) sc0 = MNEG;
                        if (kbase + 1 > qcol) sc1 = MNEG;
                        if (kbase + 2 > qcol) sc2 = MNEG;
                        if (kbase + 3 > qcol) sc3 = MNEG;
                    }
                    p[ab][0] = exp2f(sc0);
                    p[ab][1] = exp2f(sc1);
                    p[ab][2] = exp2f(sc2);
                    p[ab][3] = exp2f(sc3);
                }
                // pack P fragment: keys w*32 + 8g + {0..7} in order
                union { uint4 u; bf16x8 v; } pf;
                pf.u.x = cvtpk_bf16(p[0][0], p[0][1]);
                pf.u.y = cvtpk_bf16(p[0][2], p[0][3]);
                pf.u.z = cvtpk_bf16(p[1][0], p[1][1]);
                pf.u.w = cvtpk_bf16(p[1][2], p[1][3]);
                // PV: O^T += V^T · P^T (V natural key order, contiguous reads); L via ones-A MFMA
                __builtin_amdgcn_s_setprio(1);
                #pragma unroll
                for (int db = 0; db < 4; db++) {
                    const bf16x8 vf = *reinterpret_cast<const bf16x8*>(&vs[(db * 16 + r16) * ALD + w * 32 + koff]);
                    Ot[db] = __builtin_amdgcn_mfma_f32_16x16x32_bf16(vf, pf.v, Ot[db], 0, 0, 0);
                }
                Lacc = __builtin_amdgcn_mfma_f32_16x16x32_bf16(onesA, pf.v, Lacc, 0, 0, 0);
                __builtin_amdgcn_s_setprio(0);
            }
        }
    }
#undef PREFETCH_MACRO
#undef PF_TILE

    // epilogue: Lacc rows all equal the full column sum — no cross-lane reduce needed
    const float rl = 1.f / Lacc[0];
    const int r4 = (lane >> 4) * 4;
    #pragma unroll
    for (int db = 0; db < 4; db++) {
        ushort4 o;
        o.x = f2bf_rn(Ot[db][0] * rl);
        o.y = f2bf_rn(Ot[db][1] * rl);
        o.z = f2bf_rn(Ot[db][2] * rl);
        o.w = f2bf_rn(Ot[db][3] * rl);
        *reinterpret_cast<ushort4*>(&ctx[((size_t)b * S_ + qcol) * H_ + h * HD_ + db * 16 + r4]) = o;
    }
}

// ---------------------------------------------------------------- launch
extern "C" void kernel_launch(void* const* d_in, const int* in_sizes, int n_in,
                              void* d_out, int out_size, void* d_ws, size_t ws_size,
                              hipStream_t stream) {
    const float* x     = (const float*)d_in[0];
    const int*   mask  = (const int*)d_in[1];
    const float* normw = (const float*)d_in[2];
    const float* normb = (const float*)d_in[3];
    const float* qkvw  = (const float*)d_in[4];
    const float* qkvb  = (const float*)d_in[5];
    const float* ow    = (const float*)d_in[6];
    const float* ob    = (const float*)d_in[7];
    float* out = (float*)d_out;

    char* ws = (char*)d_ws;
    unsigned short* xn_bf   = (unsigned short*)(ws);                      //  8 MB
    unsigned short* qkvwT   = (unsigned short*)(ws + (8ull  << 20));      //  6 MB
    unsigned short* owT     = (unsigned short*)(ws + (14ull << 20));      //  2 MB
    unsigned short* Qb      = (unsigned short*)(ws + (16ull << 20));      //  8 MB [bh][s][d]
    unsigned short* Kb      = (unsigned short*)(ws + (24ull << 20));      //  8 MB [bh][s][d]
    unsigned short* Vtb     = (unsigned short*)(ws + (32ull << 20));      //  8 MB [bh][d][s]
    unsigned short* ctx_bf  = (unsigned short*)(ws + (40ull << 20));      //  8 MB

    pre_k<<<1024 + T_, 256, 0, stream>>>(qkvw, ow, qkvwT, owT, x, normw, normb, xn_bf);
    gemm_qkv_k<<<dim3(H3_ / 64, T_ / 128), 256, 0, stream>>>(xn_bf, qkvwT, qkvb, Qb, Kb, Vtb);
    attn_k<<<1024, 256, 0, stream>>>(Qb, Kb, Vtb, mask, ctx_bf);
    gemm_proj_k<<<dim3(H_ / 64, T_ / 128), 256, 0, stream>>>(ctx_bf, owT, ob, out, T_, H_, H_);
}